// Round 12
// baseline (610.213 us; speedup 1.0000x reference)
//
#include <hip/hip_runtime.h>
#include <math.h>

// Problem constants (match reference)
#define T_TOK 2048   // B*L
#define SEQ   1024   // L
#define DM    1024   // d_model
#define DI    2048   // d_inner
#define FFN   4096
#define NST   16     // d_state
#define DTR   64     // dt_rank
#define XD    96     // dt_rank + 2*d_state
#define CHK   64     // scan chunk length
#define NCHK  16     // chunks per sequence
#define SPLITK 8     // x_proj K-splits (K chunk = 256)

typedef __attribute__((ext_vector_type(8))) short short8;
typedef __attribute__((ext_vector_type(4))) float floatx4;

__device__ __forceinline__ unsigned short f2b(float f) {
  unsigned u = __float_as_uint(f);
  unsigned r = (u + 0x7fff + ((u >> 16) & 1)) >> 16;  // RNE
  return (unsigned short)r;
}
__device__ __forceinline__ float b2f(unsigned short s) {
  return __uint_as_float(((unsigned)s) << 16);
}

// async global->LDS, 16 B per lane. lds must be the wave-uniform base
// (lane 0's destination); HW adds lane*16.  Global src is per-lane.
typedef const __attribute__((address_space(1))) unsigned int g_uint;
typedef __attribute__((address_space(3))) unsigned int l_uint;
__device__ __forceinline__ void async16(void* lds, const void* g) {
  __builtin_amdgcn_global_load_lds((g_uint*)(size_t)g,
                                   (l_uint*)(unsigned)(size_t)lds, 16, 0, 0);
}

// drain global->LDS queue + workgroup barrier.
__device__ __forceinline__ void wait_barrier() {
  asm volatile("s_waitcnt vmcnt(0)\n\ts_barrier" ::: "memory");
}

// inline-asm LDS read: invisible to the compiler's auto-waitcnt pass, so it
// does NOT force a vmcnt(0) drain of in-flight global_load_lds (which write a
// DIFFERENT buffer).  Caller must s_waitcnt lgkmcnt(0) + sched_barrier(0)
// before consuming (rule #18).
__device__ __forceinline__ short8 lds_read16(const void* p) {
  short8 r;
  asm volatile("ds_read_b128 %0, %1" : "=v"(r) : "v"((unsigned)(size_t)p));
  return r;
}
__device__ __forceinline__ void lgkm0_fence() {
  asm volatile("s_waitcnt lgkmcnt(0)" ::: "memory");
  __builtin_amdgcn_sched_barrier(0);
}

// ---------------------------------------------------------------------------
// fp32 -> bf16 bulk convert (n multiple of 1024); 4 elems/thread
// ---------------------------------------------------------------------------
__global__ __launch_bounds__(256) void f2b_k(const float* __restrict__ in,
                                             unsigned short* __restrict__ out) {
  int i = blockIdx.x * 256 + threadIdx.x;
  float4 v = ((const float4*)in)[i];
  ushort4 o;
  o.x = f2b(v.x); o.y = f2b(v.y); o.z = f2b(v.z); o.w = f2b(v.w);
  ((ushort4*)out)[i] = o;
}

// two-tensor variant: converts a (na4 float4s) then b
__global__ __launch_bounds__(256) void f2b2_k(const float* __restrict__ a,
                                              unsigned short* __restrict__ oa,
                                              int na4,
                                              const float* __restrict__ b,
                                              unsigned short* __restrict__ ob) {
  int i = blockIdx.x * 256 + threadIdx.x;
  const float* in = (i < na4) ? a : b;
  unsigned short* out = (i < na4) ? oa : ob;
  int j = (i < na4) ? i : i - na4;
  float4 v = ((const float4*)in)[j];
  ushort4 o;
  o.x = f2b(v.x); o.y = f2b(v.y); o.z = f2b(v.z); o.w = f2b(v.w);
  ((ushort4*)out)[j] = o;
}

// ---------------------------------------------------------------------------
// Fused LN0+LN1: xout = LN0(x) fp32 (residual), uout = bf16(LN1(LN0(x)))
// ---------------------------------------------------------------------------
__global__ __launch_bounds__(256) void ln01_k(
    const float* __restrict__ in, const float* __restrict__ w0,
    const float* __restrict__ b0, const float* __restrict__ w1,
    const float* __restrict__ b1, float* __restrict__ xout,
    unsigned short* __restrict__ uout) {
  int t = blockIdx.x, tid = threadIdx.x;
  int wv = tid >> 6, ln = tid & 63;
  __shared__ float sm[4][4];
  float4 v = *(const float4*)(in + (size_t)t * DM + tid * 4);
  float s = v.x + v.y + v.z + v.w;
  for (int o = 32; o > 0; o >>= 1) s += __shfl_down(s, o, 64);
  if (ln == 0) sm[0][wv] = s;
  __syncthreads();
  float mu = (sm[0][0] + sm[0][1] + sm[0][2] + sm[0][3]) * (1.0f / DM);
  float d0 = v.x - mu, d1 = v.y - mu, d2 = v.z - mu, d3 = v.w - mu;
  float sq = d0 * d0 + d1 * d1 + d2 * d2 + d3 * d3;
  for (int o = 32; o > 0; o >>= 1) sq += __shfl_down(sq, o, 64);
  if (ln == 0) sm[1][wv] = sq;
  __syncthreads();
  float rs = rsqrtf((sm[1][0] + sm[1][1] + sm[1][2] + sm[1][3]) * (1.0f / DM) + 1e-5f);
  float4 w4 = *(const float4*)(w0 + tid * 4);
  float4 b4 = *(const float4*)(b0 + tid * 4);
  float r0 = d0 * rs * w4.x + b4.x, r1 = d1 * rs * w4.y + b4.y;
  float r2 = d2 * rs * w4.z + b4.z, r3 = d3 * rs * w4.w + b4.w;
  *(float4*)(xout + (size_t)t * DM + tid * 4) = make_float4(r0, r1, r2, r3);
  float s1 = r0 + r1 + r2 + r3;
  for (int o = 32; o > 0; o >>= 1) s1 += __shfl_down(s1, o, 64);
  if (ln == 0) sm[2][wv] = s1;
  __syncthreads();
  float mu1 = (sm[2][0] + sm[2][1] + sm[2][2] + sm[2][3]) * (1.0f / DM);
  float e0 = r0 - mu1, e1 = r1 - mu1, e2 = r2 - mu1, e3 = r3 - mu1;
  float sq1 = e0 * e0 + e1 * e1 + e2 * e2 + e3 * e3;
  for (int o = 32; o > 0; o >>= 1) sq1 += __shfl_down(sq1, o, 64);
  if (ln == 0) sm[3][wv] = sq1;
  __syncthreads();
  float rs1 = rsqrtf((sm[3][0] + sm[3][1] + sm[3][2] + sm[3][3]) * (1.0f / DM) + 1e-5f);
  float4 w14 = *(const float4*)(w1 + tid * 4);
  float4 b14 = *(const float4*)(b1 + tid * 4);
  ushort4 o;
  o.x = f2b(e0 * rs1 * w14.x + b14.x);
  o.y = f2b(e1 * rs1 * w14.y + b14.y);
  o.z = f2b(e2 * rs1 * w14.z + b14.z);
  o.w = f2b(e3 * rs1 * w14.w + b14.w);
  *(ushort4*)(uout + (size_t)t * DM + tid * 4) = o;
}

// ---------------------------------------------------------------------------
// 128x128 bf16 MFMA GEMM (NT), BK=64, dbuf LDS, template<SWZ> staging:
//  SWZ=1 (R7, for lda>=1024): pre-swizzled-source global_load_lds — LDS slot
//    p=r*256+tid linear; lane fetches row=p>>3, slab=(p&7)^((p>>3)&7): wave
//    reads 8 CONTIGUOUS 128-B segments/instr (8 cache lines vs 64 scattered).
//    Read slot = row*8 + (s^(row&7)).  Measured: big GEMMs 62 -> ~45 us.
//  SWZ=0 (R4, for dt_proj lda=64): one-row-per-lane staging, slab-major slots
//    (slot = slab*128+row), no XOR.  Measured fast for the tiny-lda shape;
//    SWZ=1 pattern regressed it to 143 us (R7).
// Schedule (both): stage(t+1) -> asm ds_read(t) -> lgkmcnt(0) -> MFMA ->
// vmcnt(0)+s_barrier.  Split-K via blockIdx.z.
// epi: 1 bf16 | 2 gelu(acc+bias) bf16 | 5 softplus(acc+bias) fp32 |
//      8 split-K bf16 partial (layer z of p0)
// ---------------------------------------------------------------------------
template <int SWZ>
__global__ __launch_bounds__(256) void gemm_bf16(
    const unsigned short* __restrict__ A, int lda,
    const unsigned short* __restrict__ Bw, int ldb,
    void* __restrict__ Cout, int ldc, int Kc, int epi,
    const float* __restrict__ bias, unsigned short* __restrict__ p0) {
  // flat tiles: 1024 slots of 16 B (128 rows x 8 chunks), 16 KB each
  __shared__ __align__(16) unsigned short As[2][8192];
  __shared__ __align__(16) unsigned short Bs[2][8192];
  int tid = threadIdx.x;
  int lane = tid & 63, wv = tid >> 6;
  int wr = wv >> 1, wc = wv & 1;
  int m0 = blockIdx.y * 128, n0 = blockIdx.x * 128;
  int ml = lane & 15, kq = lane >> 4;
  int kstart = blockIdx.z * Kc;
  int nt = Kc >> 6;
  floatx4 acc[4][4] = {};

  auto stage = [&](int buf, int k0) {
#pragma unroll
    for (int r = 0; r < 4; ++r) {
      if (SWZ) {
        int row = r * 32 + (tid >> 3);
        int slab = (tid & 7) ^ ((tid >> 3) & 7);
        async16(&As[buf][(r * 256 + wv * 64) * 8],
                A + (size_t)(m0 + row) * lda + k0 + slab * 8);
        async16(&Bs[buf][(r * 256 + wv * 64) * 8],
                Bw + (size_t)(n0 + row) * ldb + k0 + slab * 8);
      } else {
        int c = tid + r * 256;
        int row = c & 127, slab = c >> 7;          // per-lane source
        int cw = wv * 64 + r * 256;
        int base = ((cw >> 7) * 128 + (cw & 127)) * 8;  // wave-uniform dest
        async16(&As[buf][base], A + (size_t)(m0 + row) * lda + k0 + slab * 8);
        async16(&Bs[buf][base], Bw + (size_t)(n0 + row) * ldb + k0 + slab * 8);
      }
    }
  };
  auto compute = [&](int buf) {
#pragma unroll
    for (int ks = 0; ks < 2; ++ks) {
      int s = ks * 4 + kq;
      short8 af[4], bfr[4];
#pragma unroll
      for (int i = 0; i < 4; ++i) {
        int row = wr * 64 + i * 16 + ml;
        int slot = SWZ ? row * 8 + (s ^ (row & 7)) : s * 128 + row;
        af[i] = lds_read16(&As[buf][slot * 8]);
      }
#pragma unroll
      for (int j = 0; j < 4; ++j) {
        int row = wc * 64 + j * 16 + ml;
        int slot = SWZ ? row * 8 + (s ^ (row & 7)) : s * 128 + row;
        bfr[j] = lds_read16(&Bs[buf][slot * 8]);
      }
      lgkm0_fence();
#pragma unroll
      for (int i = 0; i < 4; ++i)
#pragma unroll
        for (int j = 0; j < 4; ++j)
          acc[i][j] =
              __builtin_amdgcn_mfma_f32_16x16x32_bf16(af[i], bfr[j], acc[i][j], 0, 0, 0);
    }
  };

  // prologue: buf0 ready
  stage(0, kstart);
  wait_barrier();
  int cur = 0;
  for (int t = 0; t < nt - 1; ++t) {
    stage(cur ^ 1, kstart + (t + 1) * 64);  // prefetch next tile (in flight
    compute(cur);                            //   during ds_read + MFMA)
    wait_barrier();                          // next tile landed; cur reads done
    cur ^= 1;
  }
  compute(cur);  // last tile, no prefetch

  unsigned short* pdstb = nullptr;
  if (epi == 8) pdstb = p0 + (size_t)blockIdx.z * T_TOK * ldc;
  // epilogue: D row = (lane>>4)*4 + r, col = lane&15
#pragma unroll
  for (int i = 0; i < 4; ++i) {
    int gm = m0 + wr * 64 + i * 16 + kq * 4;
#pragma unroll
    for (int j = 0; j < 4; ++j) {
      int gn = n0 + wc * 64 + j * 16 + ml;
#pragma unroll
      for (int r = 0; r < 4; ++r) {
        float v = acc[i][j][r];
        size_t off = (size_t)(gm + r) * ldc + gn;
        if (epi == 5) {
          float x = v + bias[gn];
          ((float*)Cout)[off] = (x > 20.f) ? x : log1pf(__expf(x));
        } else if (epi == 1) {
          ((unsigned short*)Cout)[off] = f2b(v);
        } else if (epi == 2) {
          float x = v + bias[gn];
          // gelu: 0.5x(1+tanh(u)) == x*sigmoid(2u), no tanhf libcall
          float u2 = 1.5957691216057308f * (x + 0.044715f * x * x * x);
          ((unsigned short*)Cout)[off] = f2b(x / (1.f + __expf(-u2)));
        } else {
          pdstb[off] = f2b(v);
        }
      }
    }
  }
}

// reduce 4 bf16 split-K partials (+bias +res) -> out fp32.  N = 1024 (=DM).
__global__ __launch_bounds__(256) void reduce4b_k(
    const unsigned short* __restrict__ p, float* __restrict__ out,
    const float* __restrict__ bias, const float* __restrict__ res) {
  int i = blockIdx.x * 256 + threadIdx.x;  // x4 elems
  const size_t TN = (size_t)T_TOK * DM;
  int gn = (i * 4) & (DM - 1);
  float4 bi = *(const float4*)(bias + gn);
  float v0 = bi.x, v1 = bi.y, v2 = bi.z, v3 = bi.w;
#pragma unroll
  for (int z = 0; z < 4; ++z) {
    ushort4 a = *(const ushort4*)(p + z * TN + (size_t)i * 4);
    v0 += b2f(a.x); v1 += b2f(a.y); v2 += b2f(a.z); v3 += b2f(a.w);
  }
  float4 r = *(const float4*)(res + (size_t)i * 4);
  *(float4*)(out + (size_t)i * 4) =
      make_float4(v0 + r.x, v1 + r.y, v2 + r.z, v3 + r.w);
}

// fused: reduce 4 bf16 out_proj partials + residual -> xres fp32 ; LN2 -> bf16
__global__ __launch_bounds__(256) void reduce4lnb_k(
    const unsigned short* __restrict__ p, float* __restrict__ xres,
    const float* __restrict__ w, const float* __restrict__ bb,
    unsigned short* __restrict__ uout) {
  int t = blockIdx.x, tid = threadIdx.x;
  int wv = tid >> 6, ln = tid & 63;
  __shared__ float sm[2][4];
  size_t base = (size_t)t * DM + tid * 4;
  const size_t TN = (size_t)T_TOK * DM;
  float4 r = *(const float4*)(xres + base);
  float v0 = r.x, v1 = r.y, v2 = r.z, v3 = r.w;
#pragma unroll
  for (int z = 0; z < 4; ++z) {
    ushort4 a = *(const ushort4*)(p + z * TN + base);
    v0 += b2f(a.x); v1 += b2f(a.y); v2 += b2f(a.z); v3 += b2f(a.w);
  }
  *(float4*)(xres + base) = make_float4(v0, v1, v2, v3);
  float s = v0 + v1 + v2 + v3;
  for (int o = 32; o > 0; o >>= 1) s += __shfl_down(s, o, 64);
  if (ln == 0) sm[0][wv] = s;
  __syncthreads();
  float mu = (sm[0][0] + sm[0][1] + sm[0][2] + sm[0][3]) * (1.0f / DM);
  float d0 = v0 - mu, d1 = v1 - mu, d2 = v2 - mu, d3 = v3 - mu;
  float sq = d0 * d0 + d1 * d1 + d2 * d2 + d3 * d3;
  for (int o = 32; o > 0; o >>= 1) sq += __shfl_down(sq, o, 64);
  if (ln == 0) sm[1][wv] = sq;
  __syncthreads();
  float rs = rsqrtf((sm[1][0] + sm[1][1] + sm[1][2] + sm[1][3]) * (1.0f / DM) + 1e-5f);
  float4 w4 = *(const float4*)(w + tid * 4);
  float4 bb4 = *(const float4*)(bb + tid * 4);
  ushort4 o;
  o.x = f2b(d0 * rs * w4.x + bb4.x);
  o.y = f2b(d1 * rs * w4.y + bb4.y);
  o.z = f2b(d2 * rs * w4.z + bb4.z);
  o.w = f2b(d3 * rs * w4.w + bb4.w);
  *(ushort4*)(uout + (size_t)t * DM + tid * 4) = o;
}

// ---------------------------------------------------------------------------
// x_proj split-K bf16 MFMA: part[ks][m][n] = sum_{k chunk} xcb[m,k]*W[n,k]
// ---------------------------------------------------------------------------
__global__ __launch_bounds__(256) void xproj_k(
    const unsigned short* __restrict__ xcb, const unsigned short* __restrict__ wpb,
    float* __restrict__ part) {
  __shared__ __align__(16) unsigned short As[4][64][8];
  __shared__ __align__(16) unsigned short Bs[32][96][8];
  int tid = threadIdx.x;
  int lane = tid & 63, wv = tid >> 6;
  int ml = lane & 15, kq = lane >> 4;
  int m0 = blockIdx.x * 64;
  int ks = blockIdx.y;
  int kbase = ks * 256;
  for (int e = tid; e < 3072; e += 256) {
    int row = e >> 5, slab = e & 31;
    *(int4*)&Bs[slab][row][0] = *(const int4*)(wpb + (size_t)row * DI + kbase + slab * 8);
  }
  floatx4 acc[6] = {};
  for (int s = 0; s < 8; ++s) {
    async16(&As[wv][0][0],
            xcb + (size_t)(m0 + lane) * DI + kbase + s * 32 + wv * 8);
    __syncthreads();
    short8 af = *(const short8*)&As[kq][wv * 16 + ml][0];
#pragma unroll
    for (int j = 0; j < 6; ++j) {
      short8 bf = *(const short8*)&Bs[s * 4 + kq][j * 16 + ml][0];
      acc[j] = __builtin_amdgcn_mfma_f32_16x16x32_bf16(af, bf, acc[j], 0, 0, 0);
    }
    __syncthreads();
  }
  float* dst = part + (size_t)ks * (T_TOK * XD);
#pragma unroll
  for (int j = 0; j < 6; ++j) {
    int gn = j * 16 + ml;
    int gm = m0 + wv * 16 + kq * 4;
#pragma unroll
    for (int r = 0; r < 4; ++r) dst[(size_t)(gm + r) * XD + gn] = acc[j][r];
  }
}

// reduce x_proj partials -> x_dbl fp32 [T,96]; dt part as bf16 [T,64]
__global__ __launch_bounds__(256) void xreduce_k(const float* __restrict__ part,
                                                 float* __restrict__ xdbl,
                                                 unsigned short* __restrict__ dtb) {
  int i = blockIdx.x * 256 + threadIdx.x;  // < T_TOK*XD
  float s = 0.f;
#pragma unroll
  for (int ks = 0; ks < SPLITK; ++ks) s += part[(size_t)ks * (T_TOK * XD) + i];
  xdbl[i] = s;
  int t = i / XD, c = i - t * XD;
  if (c < DTR) dtb[(size_t)t * DTR + c] = f2b(s);
}

// ---------------------------------------------------------------------------
// Causal depthwise conv (k=4) + bias + SiLU. Reads bf16 x-half of xz
// (row stride 2*DI). Emits fp32 (scan) + bf16 (x_proj).
// ---------------------------------------------------------------------------
__global__ __launch_bounds__(256) void conv_silu_k(
    const unsigned short* __restrict__ xzb, const float* __restrict__ cw,
    const float* __restrict__ cb, float* __restrict__ xc,
    unsigned short* __restrict__ xcb) {
  int idx = blockIdx.x * 256 + threadIdx.x;  // over T_TOK*DI
  int d = idx & (DI - 1);
  int t = idx >> 11;
  int l = t & (SEQ - 1);
  const unsigned short* base = xzb + (size_t)t * (2 * DI) + d;
  float4 w4 = *(const float4*)(cw + d * 4);
  float s = cb[d] + w4.w * b2f(base[0]);
  if (l >= 1) s = fmaf(w4.z, b2f(base[-(2 * DI)]), s);
  if (l >= 2) s = fmaf(w4.y, b2f(base[-2 * (2 * DI)]), s);
  if (l >= 3) s = fmaf(w4.x, b2f(base[-3 * (2 * DI)]), s);
  float y = s / (1.f + __expf(-s));  // silu
  xc[(size_t)t * DI + d] = y;
  xcb[(size_t)t * DI + d] = f2b(y);
}

// ---------------------------------------------------------------------------
// Chunked selective scan, 4 states/thread, load-batched (UB=8), with
// __launch_bounds__(256, 4): grid (1024 blocks / 256 CU) supplies exactly
// 4 waves/SIMD, so targeting 4 (not the default 8) lets the allocator use
// up to 128 VGPR — enough to keep the 8-deep load batch in registers
// (R9's VGPR=64 build re-fused the batch; R10's 2-state split regressed
// via 2x redundant dv/xv loads).  idx: [1:0]=ng, [12:2]=d, [16:13]=c, [17]=b
// ---------------------------------------------------------------------------
__global__ __launch_bounds__(256, 4) void scan1_k(
    const float* __restrict__ delta, const float* __restrict__ xc,
    const float* __restrict__ xdbl, const float* __restrict__ A_log,
    float* __restrict__ hend, float* __restrict__ aprod) {
  int idx = blockIdx.x * 256 + threadIdx.x;
  int ng = idx & 3;
  int d = (idx >> 2) & (DI - 1);
  int c = (idx >> 13) & (NCHK - 1);
  int b = idx >> 17;
  const float* ap_ = A_log + d * NST + ng * 4;
  float a0 = -__expf(ap_[0]), a1 = -__expf(ap_[1]);
  float a2 = -__expf(ap_[2]), a3 = -__expf(ap_[3]);
  float h0 = 0.f, h1 = 0.f, h2 = 0.f, h3 = 0.f;
  float q0 = 1.f, q1 = 1.f, q2 = 1.f, q3 = 1.f;
  int t = b * SEQ + c * CHK;
  const float* dp = delta + (size_t)t * DI + d;
  const float* xp = xc + (size_t)t * DI + d;
  const float* bp = xdbl + (size_t)t * XD + DTR + ng * 4;
  for (int lb = 0; lb < CHK; lb += 8) {
    float dvv[8], xvv[8];
    float4 Bv[8];
#pragma unroll
    for (int u = 0; u < 8; ++u) {
      dvv[u] = dp[(size_t)u * DI];
      xvv[u] = xp[(size_t)u * DI];
      Bv[u] = *(const float4*)(bp + u * XD);
    }
#pragma unroll
    for (int u = 0; u < 8; ++u) {
      float dv = dvv[u], xv = xvv[u];
      float4 B4 = Bv[u];
      float dx = dv * xv;
      float e0 = __expf(dv * a0), e1 = __expf(dv * a1);
      float e2 = __expf(dv * a2), e3 = __expf(dv * a3);
      q0 *= e0; q1 *= e1; q2 *= e2; q3 *= e3;
      h0 = fmaf(e0, h0, dx * B4.x);
      h1 = fmaf(e1, h1, dx * B4.y);
      h2 = fmaf(e2, h2, dx * B4.z);
      h3 = fmaf(e3, h3, dx * B4.w);
    }
    dp += 8 * DI; xp += 8 * DI; bp += 8 * XD;
  }
  size_t o = ((size_t)(b * NCHK + c) * DI + d) * NST + ng * 4;
  *(float4*)&hend[o] = make_float4(h0, h1, h2, h3);
  *(float4*)&aprod[o] = make_float4(q0, q1, q2, q3);
}

__global__ __launch_bounds__(256, 4) void scan2_k(
    const float* __restrict__ delta, const float* __restrict__ xc,
    const float* __restrict__ xdbl, const unsigned short* __restrict__ xzb,
    const float* __restrict__ A_log, const float* __restrict__ Dsk,
    const float* __restrict__ hend, const float* __restrict__ aprod,
    unsigned short* __restrict__ y) {
  int idx = blockIdx.x * 256 + threadIdx.x;
  int ng = idx & 3;
  int d = (idx >> 2) & (DI - 1);
  int c = (idx >> 13) & (NCHK - 1);
  int b = idx >> 17;
  const float* ap_ = A_log + d * NST + ng * 4;
  float a0 = -__expf(ap_[0]), a1 = -__expf(ap_[1]);
  float a2 = -__expf(ap_[2]), a3 = -__expf(ap_[3]);
  float dskip = Dsk[d];
  float h0 = 0.f, h1 = 0.f, h2 = 0.f, h3 = 0.f;
  // prefix over previous chunks: batched predicated loads (pc>=c -> (1,0)),
  // 3 groups of 5 cover pc=0..14 (c<=15); identical math for pc<c.
#pragma unroll
  for (int g = 0; g < 3; ++g) {
    float4 apv[5], hev[5];
#pragma unroll
    for (int u = 0; u < 5; ++u) {
      int pc = g * 5 + u;
      size_t o = ((size_t)(b * NCHK + pc) * DI + d) * NST + ng * 4;
      apv[u] = *(const float4*)&aprod[o];
      hev[u] = *(const float4*)&hend[o];
    }
#pragma unroll
    for (int u = 0; u < 5; ++u) {
      int pc = g * 5 + u;
      bool on = pc < c;
      float4 ap4 = apv[u], he4 = hev[u];
      h0 = fmaf(on ? ap4.x : 1.f, h0, on ? he4.x : 0.f);
      h1 = fmaf(on ? ap4.y : 1.f, h1, on ? he4.y : 0.f);
      h2 = fmaf(on ? ap4.z : 1.f, h2, on ? he4.z : 0.f);
      h3 = fmaf(on ? ap4.w : 1.f, h3, on ? he4.w : 0.f);
    }
  }
  int t = b * SEQ + c * CHK;
  const float* dp = delta + (size_t)t * DI + d;
  const float* xp = xc + (size_t)t * DI + d;
  const float* bp = xdbl + (size_t)t * XD + DTR + ng * 4;
  const float* cp = xdbl + (size_t)t * XD + DTR + NST + ng * 4;
  const unsigned short* zp = xzb + (size_t)t * (2 * DI) + DI + d;
  unsigned short* yp = y + (size_t)t * DI + d;
  for (int lb = 0; lb < CHK; lb += 8) {
    float dvv[8], xvv[8], zvv[8];
    float4 Bv[8], Cv[8];
#pragma unroll
    for (int u = 0; u < 8; ++u) {
      dvv[u] = dp[(size_t)u * DI];
      xvv[u] = xp[(size_t)u * DI];
      Bv[u] = *(const float4*)(bp + u * XD);
      Cv[u] = *(const float4*)(cp + u * XD);
      zvv[u] = b2f(zp[(size_t)u * 2 * DI]);  // broadcast within 4-lane group
    }
#pragma unroll
    for (int u = 0; u < 8; ++u) {
      float dv = dvv[u], xv = xvv[u];
      float4 B4 = Bv[u], C4 = Cv[u];
      float dx = dv * xv;
      float e0 = __expf(dv * a0), e1 = __expf(dv * a1);
      float e2 = __expf(dv * a2), e3 = __expf(dv * a3);
      h0 = fmaf(e0, h0, dx * B4.x);
      h1 = fmaf(e1, h1, dx * B4.y);
      h2 = fmaf(e2, h2, dx * B4.z);
      h3 = fmaf(e3, h3, dx * B4.w);
      float contrib = h0 * C4.x + h1 * C4.y + h2 * C4.z + h3 * C4.w;
      contrib += __shfl_xor(contrib, 1);
      contrib += __shfl_xor(contrib, 2);
      if (ng == 0) {
        float zv = zvv[u];
        float sig = zv / (1.f + __expf(-zv));
        yp[(size_t)u * DI] = f2b((contrib + xv * dskip) * sig);
      }
    }
    dp += 8 * DI; xp += 8 * DI; bp += 8 * XD; cp += 8 * XD;
    zp += 8 * 2 * DI; yp += 8 * DI;
  }
}

// ---------------------------------------------------------------------------
extern "C" void kernel_launch(void* const* d_in, const int* in_sizes, int n_in,
                              void* d_out, int out_size, void* d_ws,
                              size_t ws_size, hipStream_t stream) {
  const float* x_in      = (const float*)d_in[0];
  const float* ln0_w     = (const float*)d_in[1];
  const float* ln0_b     = (const float*)d_in[2];
  const float* ln1_w     = (const float*)d_in[3];
  const float* ln1_b     = (const float*)d_in[4];
  const float* ln2_w     = (const float*)d_in[5];
  const float* ln2_b     = (const float*)d_in[6];
  const float* in_proj_w = (const float*)d_in[7];
  const float* conv_w    = (const float*)d_in[8];
  const float* conv_b    = (const float*)d_in[9];
  const float* x_proj_w  = (const float*)d_in[10];
  const float* dt_proj_w = (const float*)d_in[11];
  const float* dt_proj_b = (const float*)d_in[12];
  const float* A_log     = (const float*)d_in[13];
  const float* D_skip    = (const float*)d_in[14];
  const float* out_proj_w= (const float*)d_in[15];
  const float* ffn_w1    = (const float*)d_in[16];
  const float* ffn_b1    = (const float*)d_in[17];
  const float* ffn_w2    = (const float*)d_in[18];
  const float* ffn_b2    = (const float*)d_in[19];
  float* out = (float*)d_out;

  // Workspace layout (floats), liveness-aliased; total 20.12M floats = 80.5 MB
  float* ws    = (float*)d_ws;
  float* xws   = ws;                     // [T,DM] fp32 residual          2.097M
  float* big   = xws + 2097152;          // xzb bf16 [T,4096] / hbf bf16  4.194M
  float* r2    = big + 4194304;          // ybf bf16 [T,DI]               2.097M
  float* xcws  = r2 + 2097152;           // xc fp32 / bf16 split-K parts  4.194M
  float* xdbl  = xcws + 4194304;         // [T,96] fp32                   0.197M
  float* dws   = xdbl + 196608;          // xcb bf16 / delta fp32         4.194M
  float* ubf_f = dws + 4194304;          // [T,DM] bf16 LN out            1.049M
  float* wbf_f = ubf_f + 1048576;        // staging region                2.097M
  // aliases (timeline-checked):
  unsigned short* xzb  = (unsigned short*)big;   // in_proj out, dies after scan2
  unsigned short* hbf  = (unsigned short*)big;   // ffn1 -> ffn2 [T,FFN] bf16
  unsigned short* ybf  = (unsigned short*)r2;    // scan2 -> out_proj
  unsigned short* ubf  = (unsigned short*)ubf_f;
  unsigned short* xcb  = (unsigned short*)dws;   // conv bf16, dies before dt_proj
  unsigned short* pbf  = (unsigned short*)xcws;  // 4-layer bf16 partials [4][T,DM]
  unsigned short* wbf  = (unsigned short*)wbf_f;
  float* part  = wbf_f;                          // xproj partials [8][T,96] 1.573M
  unsigned short* wpb = (unsigned short*)(wbf_f + 1572864);  // x_proj_w bf16
  unsigned short* dtb = (unsigned short*)(wbf_f + 1671168);  // dt bf16 [T,64]
  unsigned short* dwb = (unsigned short*)(wbf_f + 1736704);  // dt_proj_w bf16
  // scan summaries overwrite the whole staging region after dt_proj:
  float* hend  = wbf_f;                  // [1048576] = B*NCHK*DI*NST
  float* aprod = wbf_f + 1048576;        // [1048576]

  // 1: convert in_proj_w -> bf16 (4096x1024)
  f2b_k<<<(4096 * 1024) / 1024, 256, 0, stream>>>(in_proj_w, wbf);
  // 2: fused LN0+LN1 -> xws fp32, ubf bf16
  ln01_k<<<T_TOK, 256, 0, stream>>>(x_in, ln0_w, ln0_b, ln1_w, ln1_b, xws, ubf);
  // 3: in_proj -> xzb bf16 (128x128 tiles, 512 blocks)
  {
    dim3 g((2 * DI) / 128, T_TOK / 128, 1);
    gemm_bf16<1><<<g, 256, 0, stream>>>(ubf, DM, wbf, DM, xzb, 2 * DI, DM, 1,
                                        nullptr, nullptr);
  }
  // 4: causal conv + silu (bf16 in) -> xc fp32 + xcb bf16
  conv_silu_k<<<(T_TOK * DI) / 256, 256, 0, stream>>>(xzb, conv_w, conv_b, xcws, xcb);
  // 5: x_proj + dt_proj weights -> bf16 (one dispatch)
  f2b2_k<<<(XD * DI + DI * DTR) / 1024, 256, 0, stream>>>(
      x_proj_w, wpb, (XD * DI) / 4, dt_proj_w, dwb);
  // 6: x_proj split-K MFMA + reduce -> xdbl fp32, dtb bf16
  {
    dim3 g(T_TOK / 64, SPLITK);
    xproj_k<<<g, 256, 0, stream>>>(xcb, wpb, part);
    xreduce_k<<<(T_TOK * XD) / 256, 256, 0, stream>>>(part, xdbl, dtb);
  }
  // 7: dt_proj + softplus (nt=1, tiny lda=64 -> SWZ=0 staging) -> delta fp32
  {
    dim3 g(DI / 128, T_TOK / 128, 1);
    gemm_bf16<0><<<g, 256, 0, stream>>>(dtb, DTR, dwb, DTR, dws, DI, DTR, 5,
                                        dt_proj_b, nullptr);
  }
  // 8-9: chunked scan, 4 states/thread (summaries alias dead staging region)
  {
    int nthreads = 2 * NCHK * DI * 4;  // 262144
    scan1_k<<<nthreads / 256, 256, 0, stream>>>(dws, xcws, xdbl, A_log,
                                                hend, aprod);
    scan2_k<<<nthreads / 256, 256, 0, stream>>>(dws, xcws, xdbl, xzb,
                                                A_log, D_skip, hend, aprod, ybf);
  }
  // 10: out_proj split-K x4 (bf16 partials in pbf) + fused reduce+res+LN2
  f2b_k<<<(DM * DI) / 1024, 256, 0, stream>>>(out_proj_w, wbf);
  {
    dim3 g(DM / 128, T_TOK / 128, 4);
    gemm_bf16<1><<<g, 256, 0, stream>>>(ybf, DI, wbf, DI, nullptr, DM, DI / 4, 8,
                                        nullptr, pbf);
    reduce4lnb_k<<<T_TOK, 256, 0, stream>>>(pbf, xws, ln2_w, ln2_b, ubf);
  }
  // 11: ffn1 + bias + gelu -> hbf bf16 (128x128 tiles, 512 blocks)
  f2b_k<<<(FFN * DM) / 1024, 256, 0, stream>>>(ffn_w1, wbf);
  {
    dim3 g(FFN / 128, T_TOK / 128, 1);
    gemm_bf16<1><<<g, 256, 0, stream>>>(ubf, DM, wbf, DM, hbf, FFN, DM, 2, ffn_b1,
                                        nullptr);
  }
  // 12: ffn2 split-K x4 (bf16 partials in pbf) + reduce(+bias+res) -> d_out
  f2b_k<<<(DM * FFN) / 1024, 256, 0, stream>>>(ffn_w2, wbf);
  {
    dim3 g(DM / 128, T_TOK / 128, 4);
    gemm_bf16<1><<<g, 256, 0, stream>>>(hbf, FFN, wbf, FFN, nullptr, DM, FFN / 4, 8,
                                        nullptr, pbf);
    reduce4b_k<<<(T_TOK * DM) / 1024, 256, 0, stream>>>(pbf, out, ffn_b2, xws);
  }
}

// Round 14
// 390.044 us; speedup vs baseline: 1.5645x; 1.5645x over previous
//
#include <hip/hip_runtime.h>
#include <math.h>

// Problem constants (match reference)
#define T_TOK 2048   // B*L
#define SEQ   1024   // L
#define DM    1024   // d_model
#define DI    2048   // d_inner
#define FFN   4096
#define NST   16     // d_state
#define DTR   64     // dt_rank
#define XD    96     // dt_rank + 2*d_state
#define CHK   64     // scan chunk length
#define NCHK  16     // chunks per sequence
#define SPLITK 8     // x_proj K-splits (K chunk = 256)

typedef __attribute__((ext_vector_type(8))) short short8;
typedef __attribute__((ext_vector_type(4))) float floatx4;

__device__ __forceinline__ unsigned short f2b(float f) {
  unsigned u = __float_as_uint(f);
  unsigned r = (u + 0x7fff + ((u >> 16) & 1)) >> 16;  // RNE
  return (unsigned short)r;
}
__device__ __forceinline__ float b2f(unsigned short s) {
  return __uint_as_float(((unsigned)s) << 16);
}

// async global->LDS, 16 B per lane. lds must be the wave-uniform base
// (lane 0's destination); HW adds lane*16.  Global src is per-lane.
typedef const __attribute__((address_space(1))) unsigned int g_uint;
typedef __attribute__((address_space(3))) unsigned int l_uint;
__device__ __forceinline__ void async16(void* lds, const void* g) {
  __builtin_amdgcn_global_load_lds((g_uint*)(size_t)g,
                                   (l_uint*)(unsigned)(size_t)lds, 16, 0, 0);
}

// drain global->LDS queue + workgroup barrier.
__device__ __forceinline__ void wait_barrier() {
  asm volatile("s_waitcnt vmcnt(0)\n\ts_barrier" ::: "memory");
}

// inline-asm LDS read: invisible to the compiler's auto-waitcnt pass, so it
// does NOT force a vmcnt(0) drain of in-flight global_load_lds (which write a
// DIFFERENT buffer).  Caller must s_waitcnt lgkmcnt(0) + sched_barrier(0)
// before consuming (rule #18).
__device__ __forceinline__ short8 lds_read16(const void* p) {
  short8 r;
  asm volatile("ds_read_b128 %0, %1" : "=v"(r) : "v"((unsigned)(size_t)p));
  return r;
}
__device__ __forceinline__ void lgkm0_fence() {
  asm volatile("s_waitcnt lgkmcnt(0)" ::: "memory");
  __builtin_amdgcn_sched_barrier(0);
}

// ---------------------------------------------------------------------------
// fp32 -> bf16 bulk convert (n multiple of 1024); 4 elems/thread
// ---------------------------------------------------------------------------
__global__ __launch_bounds__(256) void f2b_k(const float* __restrict__ in,
                                             unsigned short* __restrict__ out) {
  int i = blockIdx.x * 256 + threadIdx.x;
  float4 v = ((const float4*)in)[i];
  ushort4 o;
  o.x = f2b(v.x); o.y = f2b(v.y); o.z = f2b(v.z); o.w = f2b(v.w);
  ((ushort4*)out)[i] = o;
}

// two-tensor variant: converts a (na4 float4s) then b
__global__ __launch_bounds__(256) void f2b2_k(const float* __restrict__ a,
                                              unsigned short* __restrict__ oa,
                                              int na4,
                                              const float* __restrict__ b,
                                              unsigned short* __restrict__ ob) {
  int i = blockIdx.x * 256 + threadIdx.x;
  const float* in = (i < na4) ? a : b;
  unsigned short* out = (i < na4) ? oa : ob;
  int j = (i < na4) ? i : i - na4;
  float4 v = ((const float4*)in)[j];
  ushort4 o;
  o.x = f2b(v.x); o.y = f2b(v.y); o.z = f2b(v.z); o.w = f2b(v.w);
  ((ushort4*)out)[j] = o;
}

// ---------------------------------------------------------------------------
// Fused LN0+LN1: xout = LN0(x) fp32 (residual), uout = bf16(LN1(LN0(x)))
// ---------------------------------------------------------------------------
__global__ __launch_bounds__(256) void ln01_k(
    const float* __restrict__ in, const float* __restrict__ w0,
    const float* __restrict__ b0, const float* __restrict__ w1,
    const float* __restrict__ b1, float* __restrict__ xout,
    unsigned short* __restrict__ uout) {
  int t = blockIdx.x, tid = threadIdx.x;
  int wv = tid >> 6, ln = tid & 63;
  __shared__ float sm[4][4];
  float4 v = *(const float4*)(in + (size_t)t * DM + tid * 4);
  float s = v.x + v.y + v.z + v.w;
  for (int o = 32; o > 0; o >>= 1) s += __shfl_down(s, o, 64);
  if (ln == 0) sm[0][wv] = s;
  __syncthreads();
  float mu = (sm[0][0] + sm[0][1] + sm[0][2] + sm[0][3]) * (1.0f / DM);
  float d0 = v.x - mu, d1 = v.y - mu, d2 = v.z - mu, d3 = v.w - mu;
  float sq = d0 * d0 + d1 * d1 + d2 * d2 + d3 * d3;
  for (int o = 32; o > 0; o >>= 1) sq += __shfl_down(sq, o, 64);
  if (ln == 0) sm[1][wv] = sq;
  __syncthreads();
  float rs = rsqrtf((sm[1][0] + sm[1][1] + sm[1][2] + sm[1][3]) * (1.0f / DM) + 1e-5f);
  float4 w4 = *(const float4*)(w0 + tid * 4);
  float4 b4 = *(const float4*)(b0 + tid * 4);
  float r0 = d0 * rs * w4.x + b4.x, r1 = d1 * rs * w4.y + b4.y;
  float r2 = d2 * rs * w4.z + b4.z, r3 = d3 * rs * w4.w + b4.w;
  *(float4*)(xout + (size_t)t * DM + tid * 4) = make_float4(r0, r1, r2, r3);
  float s1 = r0 + r1 + r2 + r3;
  for (int o = 32; o > 0; o >>= 1) s1 += __shfl_down(s1, o, 64);
  if (ln == 0) sm[2][wv] = s1;
  __syncthreads();
  float mu1 = (sm[2][0] + sm[2][1] + sm[2][2] + sm[2][3]) * (1.0f / DM);
  float e0 = r0 - mu1, e1 = r1 - mu1, e2 = r2 - mu1, e3 = r3 - mu1;
  float sq1 = e0 * e0 + e1 * e1 + e2 * e2 + e3 * e3;
  for (int o = 32; o > 0; o >>= 1) sq1 += __shfl_down(sq1, o, 64);
  if (ln == 0) sm[3][wv] = sq1;
  __syncthreads();
  float rs1 = rsqrtf((sm[3][0] + sm[3][1] + sm[3][2] + sm[3][3]) * (1.0f / DM) + 1e-5f);
  float4 w14 = *(const float4*)(w1 + tid * 4);
  float4 b14 = *(const float4*)(b1 + tid * 4);
  ushort4 o;
  o.x = f2b(e0 * rs1 * w14.x + b14.x);
  o.y = f2b(e1 * rs1 * w14.y + b14.y);
  o.z = f2b(e2 * rs1 * w14.z + b14.z);
  o.w = f2b(e3 * rs1 * w14.w + b14.w);
  *(ushort4*)(uout + (size_t)t * DM + tid * 4) = o;
}

// ---------------------------------------------------------------------------
// 128x128 bf16 MFMA GEMM (NT), BK=64, dbuf LDS, pre-swizzled-source
// global_load_lds staging (R7-proven for lda>=1024): LDS slot p=r*256+tid
// linear; lane fetches row=p>>3, slab=(p&7)^((p>>3)&7): wave reads 8
// CONTIGUOUS 128-B segments/instr.  Read slot = row*8 + (s^(row&7)).
// Schedule: stage(t+1) -> asm ds_read(t) -> lgkmcnt(0) -> MFMA ->
// vmcnt(0)+s_barrier.  Split-K via blockIdx.z.
// epi: 1 bf16 | 2 gelu(acc+bias) bf16 | 8 split-K bf16 partial (layer z)
// ---------------------------------------------------------------------------
__global__ __launch_bounds__(256) void gemm_bf16(
    const unsigned short* __restrict__ A, int lda,
    const unsigned short* __restrict__ Bw, int ldb,
    void* __restrict__ Cout, int ldc, int Kc, int epi,
    const float* __restrict__ bias, unsigned short* __restrict__ p0) {
  // flat tiles: 1024 slots of 16 B (128 rows x 8 chunks), 16 KB each
  __shared__ __align__(16) unsigned short As[2][8192];
  __shared__ __align__(16) unsigned short Bs[2][8192];
  int tid = threadIdx.x;
  int lane = tid & 63, wv = tid >> 6;
  int wr = wv >> 1, wc = wv & 1;
  int m0 = blockIdx.y * 128, n0 = blockIdx.x * 128;
  int ml = lane & 15, kq = lane >> 4;
  int kstart = blockIdx.z * Kc;
  int nt = Kc >> 6;
  floatx4 acc[4][4] = {};

  auto stage = [&](int buf, int k0) {
#pragma unroll
    for (int r = 0; r < 4; ++r) {
      int row = r * 32 + (tid >> 3);
      int slab = (tid & 7) ^ ((tid >> 3) & 7);
      async16(&As[buf][(r * 256 + wv * 64) * 8],
              A + (size_t)(m0 + row) * lda + k0 + slab * 8);
      async16(&Bs[buf][(r * 256 + wv * 64) * 8],
              Bw + (size_t)(n0 + row) * ldb + k0 + slab * 8);
    }
  };
  auto compute = [&](int buf) {
#pragma unroll
    for (int ks = 0; ks < 2; ++ks) {
      int s = ks * 4 + kq;
      short8 af[4], bfr[4];
#pragma unroll
      for (int i = 0; i < 4; ++i) {
        int row = wr * 64 + i * 16 + ml;
        af[i] = lds_read16(&As[buf][(row * 8 + (s ^ (row & 7))) * 8]);
      }
#pragma unroll
      for (int j = 0; j < 4; ++j) {
        int row = wc * 64 + j * 16 + ml;
        bfr[j] = lds_read16(&Bs[buf][(row * 8 + (s ^ (row & 7))) * 8]);
      }
      lgkm0_fence();
#pragma unroll
      for (int i = 0; i < 4; ++i)
#pragma unroll
        for (int j = 0; j < 4; ++j)
          acc[i][j] =
              __builtin_amdgcn_mfma_f32_16x16x32_bf16(af[i], bfr[j], acc[i][j], 0, 0, 0);
    }
  };

  // prologue: buf0 ready
  stage(0, kstart);
  wait_barrier();
  int cur = 0;
  for (int t = 0; t < nt - 1; ++t) {
    stage(cur ^ 1, kstart + (t + 1) * 64);  // prefetch next tile (in flight
    compute(cur);                            //   during ds_read + MFMA)
    wait_barrier();                          // next tile landed; cur reads done
    cur ^= 1;
  }
  compute(cur);  // last tile, no prefetch

  unsigned short* pdstb = nullptr;
  if (epi == 8) pdstb = p0 + (size_t)blockIdx.z * T_TOK * ldc;
  // epilogue: D row = (lane>>4)*4 + r, col = lane&15
#pragma unroll
  for (int i = 0; i < 4; ++i) {
    int gm = m0 + wr * 64 + i * 16 + kq * 4;
#pragma unroll
    for (int j = 0; j < 4; ++j) {
      int gn = n0 + wc * 64 + j * 16 + ml;
#pragma unroll
      for (int r = 0; r < 4; ++r) {
        float v = acc[i][j][r];
        size_t off = (size_t)(gm + r) * ldc + gn;
        if (epi == 1) {
          ((unsigned short*)Cout)[off] = f2b(v);
        } else if (epi == 2) {
          float x = v + bias[gn];
          // gelu: 0.5x(1+tanh(u)) == x*sigmoid(2u), no tanhf libcall
          float u2 = 1.5957691216057308f * (x + 0.044715f * x * x * x);
          ((unsigned short*)Cout)[off] = f2b(x / (1.f + __expf(-u2)));
        } else {
          pdstb[off] = f2b(v);
        }
      }
    }
  }
}

// ---------------------------------------------------------------------------
// Dedicated dt_proj kernel: delta[m,n] = softplus(dtb[m,:64].dwb[n,:64] + b[n])
// 64x128 tile, K=64 one-shot, grid (DI/128=16, T/64=32)=512 blocks (2/CU).
// A row = 64 bf16 = 128 B = 8 int4 chunks: A tile 64x8=512 chunks (2 rounds),
// B tile 128x8=1024 chunks (4 rounds).  (R13 bug: staged only 4 chunks/row ->
// k=32..63 read garbage; fixed here.)  LDS rows padded to 144 B.  Plain
// __syncthreads, no asm, no template — avoids the gemm_bf16<0> regalloc
// cliff (R7: 143us / R8-R9: <43 / R12: 160 with identical source).
// ---------------------------------------------------------------------------
__global__ __launch_bounds__(256) void dtproj_k(
    const unsigned short* __restrict__ A,   // [T,64] bf16
    const unsigned short* __restrict__ Bw,  // [DI,64] bf16
    float* __restrict__ Cout,               // [T,DI] fp32
    const float* __restrict__ bias) {
  __shared__ __align__(16) unsigned short As[64][72];    // 9 KB (144-B rows)
  __shared__ __align__(16) unsigned short Bs[128][72];   // 18 KB
  int tid = threadIdx.x;
  int lane = tid & 63, wv = tid >> 6;
  int wr = wv >> 1, wc = wv & 1;
  int m0 = blockIdx.y * 64, n0 = blockIdx.x * 128;
  int ml = lane & 15, kq = lane >> 4;
  // stage A: 64 rows x 8 chunks = 512 (2 rounds); B: 128 x 8 = 1024 (4 rounds)
#pragma unroll
  for (int r = 0; r < 2; ++r) {
    int c = tid + r * 256;
    int row = c >> 3, ch = c & 7;
    *(int4*)&As[row][ch * 8] =
        *(const int4*)(A + (size_t)(m0 + row) * DTR + ch * 8);
  }
#pragma unroll
  for (int r = 0; r < 4; ++r) {
    int c = tid + r * 256;
    int row = c >> 3, ch = c & 7;
    *(int4*)&Bs[row][ch * 8] =
        *(const int4*)(Bw + (size_t)(n0 + row) * DTR + ch * 8);
  }
  __syncthreads();
  floatx4 acc[2][4] = {};
#pragma unroll
  for (int ks = 0; ks < 2; ++ks) {
    short8 af[2], bfr[4];
#pragma unroll
    for (int i = 0; i < 2; ++i)
      af[i] = *(const short8*)&As[wr * 32 + i * 16 + ml][(ks * 4 + kq) * 8];
#pragma unroll
    for (int j = 0; j < 4; ++j)
      bfr[j] = *(const short8*)&Bs[wc * 64 + j * 16 + ml][(ks * 4 + kq) * 8];
#pragma unroll
    for (int i = 0; i < 2; ++i)
#pragma unroll
      for (int j = 0; j < 4; ++j)
        acc[i][j] =
            __builtin_amdgcn_mfma_f32_16x16x32_bf16(af[i], bfr[j], acc[i][j], 0, 0, 0);
  }
  // epilogue: softplus(acc + bias[gn]) -> fp32 [T,DI]
#pragma unroll
  for (int i = 0; i < 2; ++i) {
    int gm = m0 + wr * 32 + i * 16 + kq * 4;
#pragma unroll
    for (int j = 0; j < 4; ++j) {
      int gn = n0 + wc * 64 + j * 16 + ml;
      float bn = bias[gn];
#pragma unroll
      for (int r = 0; r < 4; ++r) {
        float x = acc[i][j][r] + bn;
        Cout[(size_t)(gm + r) * DI + gn] = (x > 20.f) ? x : log1pf(__expf(x));
      }
    }
  }
}

// reduce 4 bf16 split-K partials (+bias +res) -> out fp32.  N = 1024 (=DM).
__global__ __launch_bounds__(256) void reduce4b_k(
    const unsigned short* __restrict__ p, float* __restrict__ out,
    const float* __restrict__ bias, const float* __restrict__ res) {
  int i = blockIdx.x * 256 + threadIdx.x;  // x4 elems
  const size_t TN = (size_t)T_TOK * DM;
  int gn = (i * 4) & (DM - 1);
  float4 bi = *(const float4*)(bias + gn);
  float v0 = bi.x, v1 = bi.y, v2 = bi.z, v3 = bi.w;
#pragma unroll
  for (int z = 0; z < 4; ++z) {
    ushort4 a = *(const ushort4*)(p + z * TN + (size_t)i * 4);
    v0 += b2f(a.x); v1 += b2f(a.y); v2 += b2f(a.z); v3 += b2f(a.w);
  }
  float4 r = *(const float4*)(res + (size_t)i * 4);
  *(float4*)(out + (size_t)i * 4) =
      make_float4(v0 + r.x, v1 + r.y, v2 + r.z, v3 + r.w);
}

// fused: reduce 4 bf16 out_proj partials + residual -> xres fp32 ; LN2 -> bf16
__global__ __launch_bounds__(256) void reduce4lnb_k(
    const unsigned short* __restrict__ p, float* __restrict__ xres,
    const float* __restrict__ w, const float* __restrict__ bb,
    unsigned short* __restrict__ uout) {
  int t = blockIdx.x, tid = threadIdx.x;
  int wv = tid >> 6, ln = tid & 63;
  __shared__ float sm[2][4];
  size_t base = (size_t)t * DM + tid * 4;
  const size_t TN = (size_t)T_TOK * DM;
  float4 r = *(const float4*)(xres + base);
  float v0 = r.x, v1 = r.y, v2 = r.z, v3 = r.w;
#pragma unroll
  for (int z = 0; z < 4; ++z) {
    ushort4 a = *(const ushort4*)(p + z * TN + base);
    v0 += b2f(a.x); v1 += b2f(a.y); v2 += b2f(a.z); v3 += b2f(a.w);
  }
  *(float4*)(xres + base) = make_float4(v0, v1, v2, v3);
  float s = v0 + v1 + v2 + v3;
  for (int o = 32; o > 0; o >>= 1) s += __shfl_down(s, o, 64);
  if (ln == 0) sm[0][wv] = s;
  __syncthreads();
  float mu = (sm[0][0] + sm[0][1] + sm[0][2] + sm[0][3]) * (1.0f / DM);
  float d0 = v0 - mu, d1 = v1 - mu, d2 = v2 - mu, d3 = v3 - mu;
  float sq = d0 * d0 + d1 * d1 + d2 * d2 + d3 * d3;
  for (int o = 32; o > 0; o >>= 1) sq += __shfl_down(sq, o, 64);
  if (ln == 0) sm[1][wv] = sq;
  __syncthreads();
  float rs = rsqrtf((sm[1][0] + sm[1][1] + sm[1][2] + sm[1][3]) * (1.0f / DM) + 1e-5f);
  float4 w4 = *(const float4*)(w + tid * 4);
  float4 bb4 = *(const float4*)(bb + tid * 4);
  ushort4 o;
  o.x = f2b(d0 * rs * w4.x + bb4.x);
  o.y = f2b(d1 * rs * w4.y + bb4.y);
  o.z = f2b(d2 * rs * w4.z + bb4.z);
  o.w = f2b(d3 * rs * w4.w + bb4.w);
  *(ushort4*)(uout + (size_t)t * DM + tid * 4) = o;
}

// ---------------------------------------------------------------------------
// x_proj split-K bf16 MFMA: part[ks][m][n] = sum_{k chunk} xcb[m,k]*W[n,k]
// ---------------------------------------------------------------------------
__global__ __launch_bounds__(256) void xproj_k(
    const unsigned short* __restrict__ xcb, const unsigned short* __restrict__ wpb,
    float* __restrict__ part) {
  __shared__ __align__(16) unsigned short As[4][64][8];
  __shared__ __align__(16) unsigned short Bs[32][96][8];
  int tid = threadIdx.x;
  int lane = tid & 63, wv = tid >> 6;
  int ml = lane & 15, kq = lane >> 4;
  int m0 = blockIdx.x * 64;
  int ks = blockIdx.y;
  int kbase = ks * 256;
  for (int e = tid; e < 3072; e += 256) {
    int row = e >> 5, slab = e & 31;
    *(int4*)&Bs[slab][row][0] = *(const int4*)(wpb + (size_t)row * DI + kbase + slab * 8);
  }
  floatx4 acc[6] = {};
  for (int s = 0; s < 8; ++s) {
    async16(&As[wv][0][0],
            xcb + (size_t)(m0 + lane) * DI + kbase + s * 32 + wv * 8);
    __syncthreads();
    short8 af = *(const short8*)&As[kq][wv * 16 + ml][0];
#pragma unroll
    for (int j = 0; j < 6; ++j) {
      short8 bf = *(const short8*)&Bs[s * 4 + kq][j * 16 + ml][0];
      acc[j] = __builtin_amdgcn_mfma_f32_16x16x32_bf16(af, bf, acc[j], 0, 0, 0);
    }
    __syncthreads();
  }
  float* dst = part + (size_t)ks * (T_TOK * XD);
#pragma unroll
  for (int j = 0; j < 6; ++j) {
    int gn = j * 16 + ml;
    int gm = m0 + wv * 16 + kq * 4;
#pragma unroll
    for (int r = 0; r < 4; ++r) dst[(size_t)(gm + r) * XD + gn] = acc[j][r];
  }
}

// reduce x_proj partials -> x_dbl fp32 [T,96]; dt part as bf16 [T,64]
__global__ __launch_bounds__(256) void xreduce_k(const float* __restrict__ part,
                                                 float* __restrict__ xdbl,
                                                 unsigned short* __restrict__ dtb) {
  int i = blockIdx.x * 256 + threadIdx.x;  // < T_TOK*XD
  float s = 0.f;
#pragma unroll
  for (int ks = 0; ks < SPLITK; ++ks) s += part[(size_t)ks * (T_TOK * XD) + i];
  xdbl[i] = s;
  int t = i / XD, c = i - t * XD;
  if (c < DTR) dtb[(size_t)t * DTR + c] = f2b(s);
}

// ---------------------------------------------------------------------------
// Causal depthwise conv (k=4) + bias + SiLU. Reads bf16 x-half of xz
// (row stride 2*DI). Emits fp32 (scan) + bf16 (x_proj).
// ---------------------------------------------------------------------------
__global__ __launch_bounds__(256) void conv_silu_k(
    const unsigned short* __restrict__ xzb, const float* __restrict__ cw,
    const float* __restrict__ cb, float* __restrict__ xc,
    unsigned short* __restrict__ xcb) {
  int idx = blockIdx.x * 256 + threadIdx.x;  // over T_TOK*DI
  int d = idx & (DI - 1);
  int t = idx >> 11;
  int l = t & (SEQ - 1);
  const unsigned short* base = xzb + (size_t)t * (2 * DI) + d;
  float4 w4 = *(const float4*)(cw + d * 4);
  float s = cb[d] + w4.w * b2f(base[0]);
  if (l >= 1) s = fmaf(w4.z, b2f(base[-(2 * DI)]), s);
  if (l >= 2) s = fmaf(w4.y, b2f(base[-2 * (2 * DI)]), s);
  if (l >= 3) s = fmaf(w4.x, b2f(base[-3 * (2 * DI)]), s);
  float y = s / (1.f + __expf(-s));  // silu
  xc[(size_t)t * DI + d] = y;
  xcb[(size_t)t * DI + d] = f2b(y);
}

// ---------------------------------------------------------------------------
// Chunked selective scan, 4 states per thread, load-batched (UB=8): the
// recurrence is serial in l but loads are address-affine and independent of
// h, so batch 8 iterations' loads (one waitcnt per batch) then run the 8
// serial h-steps from registers.  (R9-proven: scan2 60.4 -> 42.7 us.)
// idx: [1:0]=ng (state group), [12:2]=d, [16:13]=chunk, [17]=b
// ---------------------------------------------------------------------------
__global__ __launch_bounds__(256) void scan1_k(
    const float* __restrict__ delta, const float* __restrict__ xc,
    const float* __restrict__ xdbl, const float* __restrict__ A_log,
    float* __restrict__ hend, float* __restrict__ aprod) {
  int idx = blockIdx.x * 256 + threadIdx.x;
  int ng = idx & 3;
  int d = (idx >> 2) & (DI - 1);
  int c = (idx >> 13) & (NCHK - 1);
  int b = idx >> 17;
  const float* ap_ = A_log + d * NST + ng * 4;
  float a0 = -__expf(ap_[0]), a1 = -__expf(ap_[1]);
  float a2 = -__expf(ap_[2]), a3 = -__expf(ap_[3]);
  float h0 = 0.f, h1 = 0.f, h2 = 0.f, h3 = 0.f;
  float q0 = 1.f, q1 = 1.f, q2 = 1.f, q3 = 1.f;
  int t = b * SEQ + c * CHK;
  const float* dp = delta + (size_t)t * DI + d;
  const float* xp = xc + (size_t)t * DI + d;
  const float* bp = xdbl + (size_t)t * XD + DTR + ng * 4;
  for (int lb = 0; lb < CHK; lb += 8) {
    float dvv[8], xvv[8];
    float4 Bv[8];
#pragma unroll
    for (int u = 0; u < 8; ++u) {
      dvv[u] = dp[(size_t)u * DI];
      xvv[u] = xp[(size_t)u * DI];
      Bv[u] = *(const float4*)(bp + u * XD);
    }
#pragma unroll
    for (int u = 0; u < 8; ++u) {
      float dv = dvv[u], xv = xvv[u];
      float4 B4 = Bv[u];
      float dx = dv * xv;
      float e0 = __expf(dv * a0), e1 = __expf(dv * a1);
      float e2 = __expf(dv * a2), e3 = __expf(dv * a3);
      q0 *= e0; q1 *= e1; q2 *= e2; q3 *= e3;
      h0 = fmaf(e0, h0, dx * B4.x);
      h1 = fmaf(e1, h1, dx * B4.y);
      h2 = fmaf(e2, h2, dx * B4.z);
      h3 = fmaf(e3, h3, dx * B4.w);
    }
    dp += 8 * DI; xp += 8 * DI; bp += 8 * XD;
  }
  size_t o = ((size_t)(b * NCHK + c) * DI + d) * NST + ng * 4;
  *(float4*)&hend[o] = make_float4(h0, h1, h2, h3);
  *(float4*)&aprod[o] = make_float4(q0, q1, q2, q3);
}

__global__ __launch_bounds__(256) void scan2_k(
    const float* __restrict__ delta, const float* __restrict__ xc,
    const float* __restrict__ xdbl, const unsigned short* __restrict__ xzb,
    const float* __restrict__ A_log, const float* __restrict__ Dsk,
    const float* __restrict__ hend, const float* __restrict__ aprod,
    unsigned short* __restrict__ y) {
  int idx = blockIdx.x * 256 + threadIdx.x;
  int ng = idx & 3;
  int d = (idx >> 2) & (DI - 1);
  int c = (idx >> 13) & (NCHK - 1);
  int b = idx >> 17;
  const float* ap_ = A_log + d * NST + ng * 4;
  float a0 = -__expf(ap_[0]), a1 = -__expf(ap_[1]);
  float a2 = -__expf(ap_[2]), a3 = -__expf(ap_[3]);
  float dskip = Dsk[d];
  float h0 = 0.f, h1 = 0.f, h2 = 0.f, h3 = 0.f;
  // prefix over previous chunks: batched predicated loads (pc>=c -> (1,0)),
  // 3 groups of 5 cover pc=0..14 (c<=15); identical math for pc<c.
#pragma unroll
  for (int g = 0; g < 3; ++g) {
    float4 apv[5], hev[5];
#pragma unroll
    for (int u = 0; u < 5; ++u) {
      int pc = g * 5 + u;
      size_t o = ((size_t)(b * NCHK + pc) * DI + d) * NST + ng * 4;
      apv[u] = *(const float4*)&aprod[o];
      hev[u] = *(const float4*)&hend[o];
    }
#pragma unroll
    for (int u = 0; u < 5; ++u) {
      int pc = g * 5 + u;
      bool on = pc < c;
      float4 ap4 = apv[u], he4 = hev[u];
      h0 = fmaf(on ? ap4.x : 1.f, h0, on ? he4.x : 0.f);
      h1 = fmaf(on ? ap4.y : 1.f, h1, on ? he4.y : 0.f);
      h2 = fmaf(on ? ap4.z : 1.f, h2, on ? he4.z : 0.f);
      h3 = fmaf(on ? ap4.w : 1.f, h3, on ? he4.w : 0.f);
    }
  }
  int t = b * SEQ + c * CHK;
  const float* dp = delta + (size_t)t * DI + d;
  const float* xp = xc + (size_t)t * DI + d;
  const float* bp = xdbl + (size_t)t * XD + DTR + ng * 4;
  const float* cp = xdbl + (size_t)t * XD + DTR + NST + ng * 4;
  const unsigned short* zp = xzb + (size_t)t * (2 * DI) + DI + d;
  unsigned short* yp = y + (size_t)t * DI + d;
  for (int lb = 0; lb < CHK; lb += 8) {
    float dvv[8], xvv[8], zvv[8];
    float4 Bv[8], Cv[8];
#pragma unroll
    for (int u = 0; u < 8; ++u) {
      dvv[u] = dp[(size_t)u * DI];
      xvv[u] = xp[(size_t)u * DI];
      Bv[u] = *(const float4*)(bp + u * XD);
      Cv[u] = *(const float4*)(cp + u * XD);
      zvv[u] = b2f(zp[(size_t)u * 2 * DI]);  // broadcast within 4-lane group
    }
#pragma unroll
    for (int u = 0; u < 8; ++u) {
      float dv = dvv[u], xv = xvv[u];
      float4 B4 = Bv[u], C4 = Cv[u];
      float dx = dv * xv;
      float e0 = __expf(dv * a0), e1 = __expf(dv * a1);
      float e2 = __expf(dv * a2), e3 = __expf(dv * a3);
      h0 = fmaf(e0, h0, dx * B4.x);
      h1 = fmaf(e1, h1, dx * B4.y);
      h2 = fmaf(e2, h2, dx * B4.z);
      h3 = fmaf(e3, h3, dx * B4.w);
      float contrib = h0 * C4.x + h1 * C4.y + h2 * C4.z + h3 * C4.w;
      contrib += __shfl_xor(contrib, 1);
      contrib += __shfl_xor(contrib, 2);
      if (ng == 0) {
        float zv = zvv[u];
        float sig = zv / (1.f + __expf(-zv));
        yp[(size_t)u * DI] = f2b((contrib + xv * dskip) * sig);
      }
    }
    dp += 8 * DI; xp += 8 * DI; bp += 8 * XD; cp += 8 * XD;
    zp += 8 * 2 * DI; yp += 8 * DI;
  }
}

// ---------------------------------------------------------------------------
extern "C" void kernel_launch(void* const* d_in, const int* in_sizes, int n_in,
                              void* d_out, int out_size, void* d_ws,
                              size_t ws_size, hipStream_t stream) {
  const float* x_in      = (const float*)d_in[0];
  const float* ln0_w     = (const float*)d_in[1];
  const float* ln0_b     = (const float*)d_in[2];
  const float* ln1_w     = (const float*)d_in[3];
  const float* ln1_b     = (const float*)d_in[4];
  const float* ln2_w     = (const float*)d_in[5];
  const float* ln2_b     = (const float*)d_in[6];
  const float* in_proj_w = (const float*)d_in[7];
  const float* conv_w    = (const float*)d_in[8];
  const float* conv_b    = (const float*)d_in[9];
  const float* x_proj_w  = (const float*)d_in[10];
  const float* dt_proj_w = (const float*)d_in[11];
  const float* dt_proj_b = (const float*)d_in[12];
  const float* A_log     = (const float*)d_in[13];
  const float* D_skip    = (const float*)d_in[14];
  const float* out_proj_w= (const float*)d_in[15];
  const float* ffn_w1    = (const float*)d_in[16];
  const float* ffn_b1    = (const float*)d_in[17];
  const float* ffn_w2    = (const float*)d_in[18];
  const float* ffn_b2    = (const float*)d_in[19];
  float* out = (float*)d_out;

  // Workspace layout (floats), liveness-aliased; total 20.12M floats = 80.5 MB
  float* ws    = (float*)d_ws;
  float* xws   = ws;                     // [T,DM] fp32 residual          2.097M
  float* big   = xws + 2097152;          // xzb bf16 [T,4096] / hbf bf16  4.194M
  float* r2    = big + 4194304;          // ybf bf16 [T,DI]               2.097M
  float* xcws  = r2 + 2097152;           // xc fp32 / bf16 split-K parts  4.194M
  float* xdbl  = xcws + 4194304;         // [T,96] fp32                   0.197M
  float* dws   = xdbl + 196608;          // xcb bf16 / delta fp32         4.194M
  float* ubf_f = dws + 4194304;          // [T,DM] bf16 LN out            1.049M
  float* wbf_f = ubf_f + 1048576;        // staging region                2.097M
  // aliases (timeline-checked):
  unsigned short* xzb  = (unsigned short*)big;   // in_proj out, dies after scan2
  unsigned short* hbf  = (unsigned short*)big;   // ffn1 -> ffn2 [T,FFN] bf16
  unsigned short* ybf  = (unsigned short*)r2;    // scan2 -> out_proj
  unsigned short* ubf  = (unsigned short*)ubf_f;
  unsigned short* xcb  = (unsigned short*)dws;   // conv bf16, dies before dt_proj
  unsigned short* pbf  = (unsigned short*)xcws;  // 4-layer bf16 partials [4][T,DM]
  unsigned short* wbf  = (unsigned short*)wbf_f;
  float* part  = wbf_f;                          // xproj partials [8][T,96] 1.573M
  unsigned short* wpb = (unsigned short*)(wbf_f + 1572864);  // x_proj_w bf16
  unsigned short* dtb = (unsigned short*)(wbf_f + 1671168);  // dt bf16 [T,64]
  unsigned short* dwb = (unsigned short*)(wbf_f + 1736704);  // dt_proj_w bf16
  // scan summaries overwrite the whole staging region after dt_proj:
  float* hend  = wbf_f;                  // [1048576] = B*NCHK*DI*NST
  float* aprod = wbf_f + 1048576;        // [1048576]

  // 1: convert in_proj_w -> bf16 (4096x1024)
  f2b_k<<<(4096 * 1024) / 1024, 256, 0, stream>>>(in_proj_w, wbf);
  // 2: fused LN0+LN1 -> xws fp32, ubf bf16
  ln01_k<<<T_TOK, 256, 0, stream>>>(x_in, ln0_w, ln0_b, ln1_w, ln1_b, xws, ubf);
  // 3: in_proj -> xzb bf16 (128x128 tiles, 512 blocks)
  {
    dim3 g((2 * DI) / 128, T_TOK / 128, 1);
    gemm_bf16<<<g, 256, 0, stream>>>(ubf, DM, wbf, DM, xzb, 2 * DI, DM, 1,
                                     nullptr, nullptr);
  }
  // 4: causal conv + silu (bf16 in) -> xc fp32 + xcb bf16
  conv_silu_k<<<(T_TOK * DI) / 256, 256, 0, stream>>>(xzb, conv_w, conv_b, xcws, xcb);
  // 5: x_proj + dt_proj weights -> bf16 (one dispatch)
  f2b2_k<<<(XD * DI + DI * DTR) / 1024, 256, 0, stream>>>(
      x_proj_w, wpb, (XD * DI) / 4, dt_proj_w, dwb);
  // 6: x_proj split-K MFMA + reduce -> xdbl fp32, dtb bf16
  {
    dim3 g(T_TOK / 64, SPLITK);
    xproj_k<<<g, 256, 0, stream>>>(xcb, wpb, part);
    xreduce_k<<<(T_TOK * XD) / 256, 256, 0, stream>>>(part, xdbl, dtb);
  }
  // 7: dt_proj + softplus -> delta fp32 (dedicated kernel, 512 blocks)
  {
    dim3 g(DI / 128, T_TOK / 64);
    dtproj_k<<<g, 256, 0, stream>>>(dtb, dwb, dws, dt_proj_b);
  }
  // 8-9: chunked scan, 4 states/thread (summaries alias dead staging region)
  {
    int nthreads = 2 * NCHK * DI * 4;  // 262144
    scan1_k<<<nthreads / 256, 256, 0, stream>>>(dws, xcws, xdbl, A_log,
                                                hend, aprod);
    scan2_k<<<nthreads / 256, 256, 0, stream>>>(dws, xcws, xdbl, xzb,
                                                A_log, D_skip, hend, aprod, ybf);
  }
  // 10: out_proj split-K x4 (bf16 partials in pbf) + fused reduce+res+LN2
  f2b_k<<<(DM * DI) / 1024, 256, 0, stream>>>(out_proj_w, wbf);
  {
    dim3 g(DM / 128, T_TOK / 128, 4);
    gemm_bf16<<<g, 256, 0, stream>>>(ybf, DI, wbf, DI, nullptr, DM, DI / 4, 8,
                                     nullptr, pbf);
    reduce4lnb_k<<<T_TOK, 256, 0, stream>>>(pbf, xws, ln2_w, ln2_b, ubf);
  }
  // 11: ffn1 + bias + gelu -> hbf bf16 (128x128 tiles, 512 blocks)
  f2b_k<<<(FFN * DM) / 1024, 256, 0, stream>>>(ffn_w1, wbf);
  {
    dim3 g(FFN / 128, T_TOK / 128, 1);
    gemm_bf16<<<g, 256, 0, stream>>>(ubf, DM, wbf, DM, hbf, FFN, DM, 2, ffn_b1,
                                     nullptr);
  }
  // 12: ffn2 split-K x4 (bf16 partials in pbf) + reduce(+bias+res) -> d_out
  f2b_k<<<(DM * FFN) / 1024, 256, 0, stream>>>(ffn_w2, wbf);
  {
    dim3 g(DM / 128, T_TOK / 128, 4);
    gemm_bf16<<<g, 256, 0, stream>>>(hbf, FFN, wbf, FFN, nullptr, DM, FFN / 4, 8,
                                     nullptr, pbf);
    reduce4b_k<<<(T_TOK * DM) / 1024, 256, 0, stream>>>(pbf, out, ffn_b2, xws);
  }
}

// Round 15
// 384.248 us; speedup vs baseline: 1.5881x; 1.0151x over previous
//
#include <hip/hip_runtime.h>
#include <math.h>

// Problem constants (match reference)
#define T_TOK 2048   // B*L
#define SEQ   1024   // L
#define DM    1024   // d_model
#define DI    2048   // d_inner
#define FFN   4096
#define NST   16     // d_state
#define DTR   64     // dt_rank
#define XD    96     // dt_rank + 2*d_state
#define CHK   64     // scan chunk length
#define NCHK  16     // chunks per sequence
#define SPLITK 8     // x_proj K-splits (K chunk = 256)

typedef __attribute__((ext_vector_type(8))) short short8;
typedef __attribute__((ext_vector_type(4))) float floatx4;

__device__ __forceinline__ unsigned short f2b(float f) {
  unsigned u = __float_as_uint(f);
  unsigned r = (u + 0x7fff + ((u >> 16) & 1)) >> 16;  // RNE
  return (unsigned short)r;
}
__device__ __forceinline__ float b2f(unsigned short s) {
  return __uint_as_float(((unsigned)s) << 16);
}

// async global->LDS, 16 B per lane. lds must be the wave-uniform base
// (lane 0's destination); HW adds lane*16.  Global src is per-lane.
typedef const __attribute__((address_space(1))) unsigned int g_uint;
typedef __attribute__((address_space(3))) unsigned int l_uint;
__device__ __forceinline__ void async16(void* lds, const void* g) {
  __builtin_amdgcn_global_load_lds((g_uint*)(size_t)g,
                                   (l_uint*)(unsigned)(size_t)lds, 16, 0, 0);
}

// drain global->LDS queue + workgroup barrier.
__device__ __forceinline__ void wait_barrier() {
  asm volatile("s_waitcnt vmcnt(0)\n\ts_barrier" ::: "memory");
}

// inline-asm LDS read: invisible to the compiler's auto-waitcnt pass, so it
// does NOT force a vmcnt(0) drain of in-flight global_load_lds (which write a
// DIFFERENT buffer).  Caller must s_waitcnt lgkmcnt(0) + sched_barrier(0)
// before consuming (rule #18).
__device__ __forceinline__ short8 lds_read16(const void* p) {
  short8 r;
  asm volatile("ds_read_b128 %0, %1" : "=v"(r) : "v"((unsigned)(size_t)p));
  return r;
}
__device__ __forceinline__ void lgkm0_fence() {
  asm volatile("s_waitcnt lgkmcnt(0)" ::: "memory");
  __builtin_amdgcn_sched_barrier(0);
}

// ---------------------------------------------------------------------------
// fp32 -> bf16 bulk convert (n multiple of 1024); 4 elems/thread
// ---------------------------------------------------------------------------
__global__ __launch_bounds__(256) void f2b_k(const float* __restrict__ in,
                                             unsigned short* __restrict__ out) {
  int i = blockIdx.x * 256 + threadIdx.x;
  float4 v = ((const float4*)in)[i];
  ushort4 o;
  o.x = f2b(v.x); o.y = f2b(v.y); o.z = f2b(v.z); o.w = f2b(v.w);
  ((ushort4*)out)[i] = o;
}

// two-tensor variant: converts a (na4 float4s) then b
__global__ __launch_bounds__(256) void f2b2_k(const float* __restrict__ a,
                                              unsigned short* __restrict__ oa,
                                              int na4,
                                              const float* __restrict__ b,
                                              unsigned short* __restrict__ ob) {
  int i = blockIdx.x * 256 + threadIdx.x;
  const float* in = (i < na4) ? a : b;
  unsigned short* out = (i < na4) ? oa : ob;
  int j = (i < na4) ? i : i - na4;
  float4 v = ((const float4*)in)[j];
  ushort4 o;
  o.x = f2b(v.x); o.y = f2b(v.y); o.z = f2b(v.z); o.w = f2b(v.w);
  ((ushort4*)out)[j] = o;
}

// ---------------------------------------------------------------------------
// Fused LN0+LN1: xout = LN0(x) fp32 (residual), uout = bf16(LN1(LN0(x)))
// ---------------------------------------------------------------------------
__global__ __launch_bounds__(256) void ln01_k(
    const float* __restrict__ in, const float* __restrict__ w0,
    const float* __restrict__ b0, const float* __restrict__ w1,
    const float* __restrict__ b1, float* __restrict__ xout,
    unsigned short* __restrict__ uout) {
  int t = blockIdx.x, tid = threadIdx.x;
  int wv = tid >> 6, ln = tid & 63;
  __shared__ float sm[4][4];
  float4 v = *(const float4*)(in + (size_t)t * DM + tid * 4);
  float s = v.x + v.y + v.z + v.w;
  for (int o = 32; o > 0; o >>= 1) s += __shfl_down(s, o, 64);
  if (ln == 0) sm[0][wv] = s;
  __syncthreads();
  float mu = (sm[0][0] + sm[0][1] + sm[0][2] + sm[0][3]) * (1.0f / DM);
  float d0 = v.x - mu, d1 = v.y - mu, d2 = v.z - mu, d3 = v.w - mu;
  float sq = d0 * d0 + d1 * d1 + d2 * d2 + d3 * d3;
  for (int o = 32; o > 0; o >>= 1) sq += __shfl_down(sq, o, 64);
  if (ln == 0) sm[1][wv] = sq;
  __syncthreads();
  float rs = rsqrtf((sm[1][0] + sm[1][1] + sm[1][2] + sm[1][3]) * (1.0f / DM) + 1e-5f);
  float4 w4 = *(const float4*)(w0 + tid * 4);
  float4 b4 = *(const float4*)(b0 + tid * 4);
  float r0 = d0 * rs * w4.x + b4.x, r1 = d1 * rs * w4.y + b4.y;
  float r2 = d2 * rs * w4.z + b4.z, r3 = d3 * rs * w4.w + b4.w;
  *(float4*)(xout + (size_t)t * DM + tid * 4) = make_float4(r0, r1, r2, r3);
  float s1 = r0 + r1 + r2 + r3;
  for (int o = 32; o > 0; o >>= 1) s1 += __shfl_down(s1, o, 64);
  if (ln == 0) sm[2][wv] = s1;
  __syncthreads();
  float mu1 = (sm[2][0] + sm[2][1] + sm[2][2] + sm[2][3]) * (1.0f / DM);
  float e0 = r0 - mu1, e1 = r1 - mu1, e2 = r2 - mu1, e3 = r3 - mu1;
  float sq1 = e0 * e0 + e1 * e1 + e2 * e2 + e3 * e3;
  for (int o = 32; o > 0; o >>= 1) sq1 += __shfl_down(sq1, o, 64);
  if (ln == 0) sm[3][wv] = sq1;
  __syncthreads();
  float rs1 = rsqrtf((sm[3][0] + sm[3][1] + sm[3][2] + sm[3][3]) * (1.0f / DM) + 1e-5f);
  float4 w14 = *(const float4*)(w1 + tid * 4);
  float4 b14 = *(const float4*)(b1 + tid * 4);
  ushort4 o;
  o.x = f2b(e0 * rs1 * w14.x + b14.x);
  o.y = f2b(e1 * rs1 * w14.y + b14.y);
  o.z = f2b(e2 * rs1 * w14.z + b14.z);
  o.w = f2b(e3 * rs1 * w14.w + b14.w);
  *(ushort4*)(uout + (size_t)t * DM + tid * 4) = o;
}

// ---------------------------------------------------------------------------
// 128x128 bf16 MFMA GEMM (NT), BK=64, dbuf LDS, pre-swizzled-source
// global_load_lds staging (R7-proven for lda>=1024): LDS slot p=r*256+tid
// linear; lane fetches row=p>>3, slab=(p&7)^((p>>3)&7): wave reads 8
// CONTIGUOUS 128-B segments/instr.  Read slot = row*8 + (s^(row&7)).
// Schedule: stage(t+1) -> asm ds_read(t) -> lgkmcnt(0) -> MFMA ->
// vmcnt(0)+s_barrier.  Split-K via blockIdx.z.
// epi: 1 bf16 | 2 gelu(acc+bias) bf16 | 8 split-K bf16 partial (layer z)
// ---------------------------------------------------------------------------
__global__ __launch_bounds__(256) void gemm_bf16(
    const unsigned short* __restrict__ A, int lda,
    const unsigned short* __restrict__ Bw, int ldb,
    void* __restrict__ Cout, int ldc, int Kc, int epi,
    const float* __restrict__ bias, unsigned short* __restrict__ p0) {
  // flat tiles: 1024 slots of 16 B (128 rows x 8 chunks), 16 KB each
  __shared__ __align__(16) unsigned short As[2][8192];
  __shared__ __align__(16) unsigned short Bs[2][8192];
  int tid = threadIdx.x;
  int lane = tid & 63, wv = tid >> 6;
  int wr = wv >> 1, wc = wv & 1;
  int m0 = blockIdx.y * 128, n0 = blockIdx.x * 128;
  int ml = lane & 15, kq = lane >> 4;
  int kstart = blockIdx.z * Kc;
  int nt = Kc >> 6;
  floatx4 acc[4][4] = {};

  auto stage = [&](int buf, int k0) {
#pragma unroll
    for (int r = 0; r < 4; ++r) {
      int row = r * 32 + (tid >> 3);
      int slab = (tid & 7) ^ ((tid >> 3) & 7);
      async16(&As[buf][(r * 256 + wv * 64) * 8],
              A + (size_t)(m0 + row) * lda + k0 + slab * 8);
      async16(&Bs[buf][(r * 256 + wv * 64) * 8],
              Bw + (size_t)(n0 + row) * ldb + k0 + slab * 8);
    }
  };
  auto compute = [&](int buf) {
#pragma unroll
    for (int ks = 0; ks < 2; ++ks) {
      int s = ks * 4 + kq;
      short8 af[4], bfr[4];
#pragma unroll
      for (int i = 0; i < 4; ++i) {
        int row = wr * 64 + i * 16 + ml;
        af[i] = lds_read16(&As[buf][(row * 8 + (s ^ (row & 7))) * 8]);
      }
#pragma unroll
      for (int j = 0; j < 4; ++j) {
        int row = wc * 64 + j * 16 + ml;
        bfr[j] = lds_read16(&Bs[buf][(row * 8 + (s ^ (row & 7))) * 8]);
      }
      lgkm0_fence();
#pragma unroll
      for (int i = 0; i < 4; ++i)
#pragma unroll
        for (int j = 0; j < 4; ++j)
          acc[i][j] =
              __builtin_amdgcn_mfma_f32_16x16x32_bf16(af[i], bfr[j], acc[i][j], 0, 0, 0);
    }
  };

  // prologue: buf0 ready
  stage(0, kstart);
  wait_barrier();
  int cur = 0;
  for (int t = 0; t < nt - 1; ++t) {
    stage(cur ^ 1, kstart + (t + 1) * 64);  // prefetch next tile (in flight
    compute(cur);                            //   during ds_read + MFMA)
    wait_barrier();                          // next tile landed; cur reads done
    cur ^= 1;
  }
  compute(cur);  // last tile, no prefetch

  unsigned short* pdstb = nullptr;
  if (epi == 8) pdstb = p0 + (size_t)blockIdx.z * T_TOK * ldc;
  // epilogue: D row = (lane>>4)*4 + r, col = lane&15
#pragma unroll
  for (int i = 0; i < 4; ++i) {
    int gm = m0 + wr * 64 + i * 16 + kq * 4;
#pragma unroll
    for (int j = 0; j < 4; ++j) {
      int gn = n0 + wc * 64 + j * 16 + ml;
#pragma unroll
      for (int r = 0; r < 4; ++r) {
        float v = acc[i][j][r];
        size_t off = (size_t)(gm + r) * ldc + gn;
        if (epi == 1) {
          ((unsigned short*)Cout)[off] = f2b(v);
        } else if (epi == 2) {
          float x = v + bias[gn];
          // gelu: 0.5x(1+tanh(u)) == x*sigmoid(2u), no tanhf libcall
          float u2 = 1.5957691216057308f * (x + 0.044715f * x * x * x);
          ((unsigned short*)Cout)[off] = f2b(x / (1.f + __expf(-u2)));
        } else {
          pdstb[off] = f2b(v);
        }
      }
    }
  }
}

// ---------------------------------------------------------------------------
// Dedicated dt_proj kernel: delta[m,n] = softplus(dtb[m,:64].dwb[n,:64] + b[n])
// 64x128 tile, K=64 one-shot, grid (DI/128=16, T/64=32)=512 blocks (2/CU).
// A row = 64 bf16 = 128 B = 8 int4 chunks: A tile 64x8=512 chunks (2 rounds),
// B tile 128x8=1024 chunks (4 rounds).  LDS rows padded to 144 B.  Plain
// __syncthreads, no asm, no template — avoids the gemm_bf16<0> regalloc
// cliff (R7: 143us / R8-R9: <43 / R12: 160 with identical source).
// R14: verified fast (left top-5), total 429 -> 390.
// ---------------------------------------------------------------------------
__global__ __launch_bounds__(256) void dtproj_k(
    const unsigned short* __restrict__ A,   // [T,64] bf16
    const unsigned short* __restrict__ Bw,  // [DI,64] bf16
    float* __restrict__ Cout,               // [T,DI] fp32
    const float* __restrict__ bias) {
  __shared__ __align__(16) unsigned short As[64][72];    // 9 KB (144-B rows)
  __shared__ __align__(16) unsigned short Bs[128][72];   // 18 KB
  int tid = threadIdx.x;
  int lane = tid & 63, wv = tid >> 6;
  int wr = wv >> 1, wc = wv & 1;
  int m0 = blockIdx.y * 64, n0 = blockIdx.x * 128;
  int ml = lane & 15, kq = lane >> 4;
  // stage A: 64 rows x 8 chunks = 512 (2 rounds); B: 128 x 8 = 1024 (4 rounds)
#pragma unroll
  for (int r = 0; r < 2; ++r) {
    int c = tid + r * 256;
    int row = c >> 3, ch = c & 7;
    *(int4*)&As[row][ch * 8] =
        *(const int4*)(A + (size_t)(m0 + row) * DTR + ch * 8);
  }
#pragma unroll
  for (int r = 0; r < 4; ++r) {
    int c = tid + r * 256;
    int row = c >> 3, ch = c & 7;
    *(int4*)&Bs[row][ch * 8] =
        *(const int4*)(Bw + (size_t)(n0 + row) * DTR + ch * 8);
  }
  __syncthreads();
  floatx4 acc[2][4] = {};
#pragma unroll
  for (int ks = 0; ks < 2; ++ks) {
    short8 af[2], bfr[4];
#pragma unroll
    for (int i = 0; i < 2; ++i)
      af[i] = *(const short8*)&As[wr * 32 + i * 16 + ml][(ks * 4 + kq) * 8];
#pragma unroll
    for (int j = 0; j < 4; ++j)
      bfr[j] = *(const short8*)&Bs[wc * 64 + j * 16 + ml][(ks * 4 + kq) * 8];
#pragma unroll
    for (int i = 0; i < 2; ++i)
#pragma unroll
      for (int j = 0; j < 4; ++j)
        acc[i][j] =
            __builtin_amdgcn_mfma_f32_16x16x32_bf16(af[i], bfr[j], acc[i][j], 0, 0, 0);
  }
  // epilogue: softplus(acc + bias[gn]) -> fp32 [T,DI]
#pragma unroll
  for (int i = 0; i < 2; ++i) {
    int gm = m0 + wr * 32 + i * 16 + kq * 4;
#pragma unroll
    for (int j = 0; j < 4; ++j) {
      int gn = n0 + wc * 64 + j * 16 + ml;
      float bn = bias[gn];
#pragma unroll
      for (int r = 0; r < 4; ++r) {
        float x = acc[i][j][r] + bn;
        Cout[(size_t)(gm + r) * DI + gn] = (x > 20.f) ? x : log1pf(__expf(x));
      }
    }
  }
}

// reduce 4 bf16 split-K partials (+bias +res) -> out fp32.  N = 1024 (=DM).
__global__ __launch_bounds__(256) void reduce4b_k(
    const unsigned short* __restrict__ p, float* __restrict__ out,
    const float* __restrict__ bias, const float* __restrict__ res) {
  int i = blockIdx.x * 256 + threadIdx.x;  // x4 elems
  const size_t TN = (size_t)T_TOK * DM;
  int gn = (i * 4) & (DM - 1);
  float4 bi = *(const float4*)(bias + gn);
  float v0 = bi.x, v1 = bi.y, v2 = bi.z, v3 = bi.w;
#pragma unroll
  for (int z = 0; z < 4; ++z) {
    ushort4 a = *(const ushort4*)(p + z * TN + (size_t)i * 4);
    v0 += b2f(a.x); v1 += b2f(a.y); v2 += b2f(a.z); v3 += b2f(a.w);
  }
  float4 r = *(const float4*)(res + (size_t)i * 4);
  *(float4*)(out + (size_t)i * 4) =
      make_float4(v0 + r.x, v1 + r.y, v2 + r.z, v3 + r.w);
}

// fused: reduce 4 bf16 out_proj partials + residual -> xres fp32 ; LN2 -> bf16
__global__ __launch_bounds__(256) void reduce4lnb_k(
    const unsigned short* __restrict__ p, float* __restrict__ xres,
    const float* __restrict__ w, const float* __restrict__ bb,
    unsigned short* __restrict__ uout) {
  int t = blockIdx.x, tid = threadIdx.x;
  int wv = tid >> 6, ln = tid & 63;
  __shared__ float sm[2][4];
  size_t base = (size_t)t * DM + tid * 4;
  const size_t TN = (size_t)T_TOK * DM;
  float4 r = *(const float4*)(xres + base);
  float v0 = r.x, v1 = r.y, v2 = r.z, v3 = r.w;
#pragma unroll
  for (int z = 0; z < 4; ++z) {
    ushort4 a = *(const ushort4*)(p + z * TN + base);
    v0 += b2f(a.x); v1 += b2f(a.y); v2 += b2f(a.z); v3 += b2f(a.w);
  }
  *(float4*)(xres + base) = make_float4(v0, v1, v2, v3);
  float s = v0 + v1 + v2 + v3;
  for (int o = 32; o > 0; o >>= 1) s += __shfl_down(s, o, 64);
  if (ln == 0) sm[0][wv] = s;
  __syncthreads();
  float mu = (sm[0][0] + sm[0][1] + sm[0][2] + sm[0][3]) * (1.0f / DM);
  float d0 = v0 - mu, d1 = v1 - mu, d2 = v2 - mu, d3 = v3 - mu;
  float sq = d0 * d0 + d1 * d1 + d2 * d2 + d3 * d3;
  for (int o = 32; o > 0; o >>= 1) sq += __shfl_down(sq, o, 64);
  if (ln == 0) sm[1][wv] = sq;
  __syncthreads();
  float rs = rsqrtf((sm[1][0] + sm[1][1] + sm[1][2] + sm[1][3]) * (1.0f / DM) + 1e-5f);
  float4 w4 = *(const float4*)(w + tid * 4);
  float4 bb4 = *(const float4*)(bb + tid * 4);
  ushort4 o;
  o.x = f2b(d0 * rs * w4.x + bb4.x);
  o.y = f2b(d1 * rs * w4.y + bb4.y);
  o.z = f2b(d2 * rs * w4.z + bb4.z);
  o.w = f2b(d3 * rs * w4.w + bb4.w);
  *(ushort4*)(uout + (size_t)t * DM + tid * 4) = o;
}

// ---------------------------------------------------------------------------
// x_proj split-K bf16 MFMA: part[ks][m][n] = sum_{k chunk} xcb[m,k]*W[n,k]
// ---------------------------------------------------------------------------
__global__ __launch_bounds__(256) void xproj_k(
    const unsigned short* __restrict__ xcb, const unsigned short* __restrict__ wpb,
    float* __restrict__ part) {
  __shared__ __align__(16) unsigned short As[4][64][8];
  __shared__ __align__(16) unsigned short Bs[32][96][8];
  int tid = threadIdx.x;
  int lane = tid & 63, wv = tid >> 6;
  int ml = lane & 15, kq = lane >> 4;
  int m0 = blockIdx.x * 64;
  int ks = blockIdx.y;
  int kbase = ks * 256;
  for (int e = tid; e < 3072; e += 256) {
    int row = e >> 5, slab = e & 31;
    *(int4*)&Bs[slab][row][0] = *(const int4*)(wpb + (size_t)row * DI + kbase + slab * 8);
  }
  floatx4 acc[6] = {};
  for (int s = 0; s < 8; ++s) {
    async16(&As[wv][0][0],
            xcb + (size_t)(m0 + lane) * DI + kbase + s * 32 + wv * 8);
    __syncthreads();
    short8 af = *(const short8*)&As[kq][wv * 16 + ml][0];
#pragma unroll
    for (int j = 0; j < 6; ++j) {
      short8 bf = *(const short8*)&Bs[s * 4 + kq][j * 16 + ml][0];
      acc[j] = __builtin_amdgcn_mfma_f32_16x16x32_bf16(af, bf, acc[j], 0, 0, 0);
    }
    __syncthreads();
  }
  float* dst = part + (size_t)ks * (T_TOK * XD);
#pragma unroll
  for (int j = 0; j < 6; ++j) {
    int gn = j * 16 + ml;
    int gm = m0 + wv * 16 + kq * 4;
#pragma unroll
    for (int r = 0; r < 4; ++r) dst[(size_t)(gm + r) * XD + gn] = acc[j][r];
  }
}

// reduce x_proj partials -> x_dbl fp32 [T,96]; dt part as bf16 [T,64]
__global__ __launch_bounds__(256) void xreduce_k(const float* __restrict__ part,
                                                 float* __restrict__ xdbl,
                                                 unsigned short* __restrict__ dtb) {
  int i = blockIdx.x * 256 + threadIdx.x;  // < T_TOK*XD
  float s = 0.f;
#pragma unroll
  for (int ks = 0; ks < SPLITK; ++ks) s += part[(size_t)ks * (T_TOK * XD) + i];
  xdbl[i] = s;
  int t = i / XD, c = i - t * XD;
  if (c < DTR) dtb[(size_t)t * DTR + c] = f2b(s);
}

// ---------------------------------------------------------------------------
// Causal depthwise conv (k=4) + bias + SiLU. Reads bf16 x-half of xz
// (row stride 2*DI). Emits fp32 (scan) + bf16 (x_proj).
// ---------------------------------------------------------------------------
__global__ __launch_bounds__(256) void conv_silu_k(
    const unsigned short* __restrict__ xzb, const float* __restrict__ cw,
    const float* __restrict__ cb, float* __restrict__ xc,
    unsigned short* __restrict__ xcb) {
  int idx = blockIdx.x * 256 + threadIdx.x;  // over T_TOK*DI
  int d = idx & (DI - 1);
  int t = idx >> 11;
  int l = t & (SEQ - 1);
  const unsigned short* base = xzb + (size_t)t * (2 * DI) + d;
  float4 w4 = *(const float4*)(cw + d * 4);
  float s = cb[d] + w4.w * b2f(base[0]);
  if (l >= 1) s = fmaf(w4.z, b2f(base[-(2 * DI)]), s);
  if (l >= 2) s = fmaf(w4.y, b2f(base[-2 * (2 * DI)]), s);
  if (l >= 3) s = fmaf(w4.x, b2f(base[-3 * (2 * DI)]), s);
  float y = s / (1.f + __expf(-s));  // silu
  xc[(size_t)t * DI + d] = y;
  xcb[(size_t)t * DI + d] = f2b(y);
}

// ---------------------------------------------------------------------------
// Chunked selective scan, 4 states/thread, load-batched (UB=8), with
// __launch_bounds__(256, 4): grid (1024 blocks / 256 CU) supplies exactly
// 4 waves/SIMD; the default 8-waves/SIMD target capped VGPR at 64 and
// re-fused the 8-deep load batch (R9/R14: VGPR=64, scan2 42.5us).  The
// (256,4) hint raises the cap to 128 so the batch (8x float4 Bv + Cv +
// scalars ~100 VGPR) stays in registers; occupancy unchanged (grid-capped).
// idx: [1:0]=ng (state group), [12:2]=d, [16:13]=chunk, [17]=b
// ---------------------------------------------------------------------------
__global__ __launch_bounds__(256, 4) void scan1_k(
    const float* __restrict__ delta, const float* __restrict__ xc,
    const float* __restrict__ xdbl, const float* __restrict__ A_log,
    float* __restrict__ hend, float* __restrict__ aprod) {
  int idx = blockIdx.x * 256 + threadIdx.x;
  int ng = idx & 3;
  int d = (idx >> 2) & (DI - 1);
  int c = (idx >> 13) & (NCHK - 1);
  int b = idx >> 17;
  const float* ap_ = A_log + d * NST + ng * 4;
  float a0 = -__expf(ap_[0]), a1 = -__expf(ap_[1]);
  float a2 = -__expf(ap_[2]), a3 = -__expf(ap_[3]);
  float h0 = 0.f, h1 = 0.f, h2 = 0.f, h3 = 0.f;
  float q0 = 1.f, q1 = 1.f, q2 = 1.f, q3 = 1.f;
  int t = b * SEQ + c * CHK;
  const float* dp = delta + (size_t)t * DI + d;
  const float* xp = xc + (size_t)t * DI + d;
  const float* bp = xdbl + (size_t)t * XD + DTR + ng * 4;
  for (int lb = 0; lb < CHK; lb += 8) {
    float dvv[8], xvv[8];
    float4 Bv[8];
#pragma unroll
    for (int u = 0; u < 8; ++u) {
      dvv[u] = dp[(size_t)u * DI];
      xvv[u] = xp[(size_t)u * DI];
      Bv[u] = *(const float4*)(bp + u * XD);
    }
#pragma unroll
    for (int u = 0; u < 8; ++u) {
      float dv = dvv[u], xv = xvv[u];
      float4 B4 = Bv[u];
      float dx = dv * xv;
      float e0 = __expf(dv * a0), e1 = __expf(dv * a1);
      float e2 = __expf(dv * a2), e3 = __expf(dv * a3);
      q0 *= e0; q1 *= e1; q2 *= e2; q3 *= e3;
      h0 = fmaf(e0, h0, dx * B4.x);
      h1 = fmaf(e1, h1, dx * B4.y);
      h2 = fmaf(e2, h2, dx * B4.z);
      h3 = fmaf(e3, h3, dx * B4.w);
    }
    dp += 8 * DI; xp += 8 * DI; bp += 8 * XD;
  }
  size_t o = ((size_t)(b * NCHK + c) * DI + d) * NST + ng * 4;
  *(float4*)&hend[o] = make_float4(h0, h1, h2, h3);
  *(float4*)&aprod[o] = make_float4(q0, q1, q2, q3);
}

__global__ __launch_bounds__(256, 4) void scan2_k(
    const float* __restrict__ delta, const float* __restrict__ xc,
    const float* __restrict__ xdbl, const unsigned short* __restrict__ xzb,
    const float* __restrict__ A_log, const float* __restrict__ Dsk,
    const float* __restrict__ hend, const float* __restrict__ aprod,
    unsigned short* __restrict__ y) {
  int idx = blockIdx.x * 256 + threadIdx.x;
  int ng = idx & 3;
  int d = (idx >> 2) & (DI - 1);
  int c = (idx >> 13) & (NCHK - 1);
  int b = idx >> 17;
  const float* ap_ = A_log + d * NST + ng * 4;
  float a0 = -__expf(ap_[0]), a1 = -__expf(ap_[1]);
  float a2 = -__expf(ap_[2]), a3 = -__expf(ap_[3]);
  float dskip = Dsk[d];
  float h0 = 0.f, h1 = 0.f, h2 = 0.f, h3 = 0.f;
  // prefix over previous chunks: batched predicated loads (pc>=c -> (1,0)),
  // 3 groups of 5 cover pc=0..14 (c<=15); identical math for pc<c.
#pragma unroll
  for (int g = 0; g < 3; ++g) {
    float4 apv[5], hev[5];
#pragma unroll
    for (int u = 0; u < 5; ++u) {
      int pc = g * 5 + u;
      size_t o = ((size_t)(b * NCHK + pc) * DI + d) * NST + ng * 4;
      apv[u] = *(const float4*)&aprod[o];
      hev[u] = *(const float4*)&hend[o];
    }
#pragma unroll
    for (int u = 0; u < 5; ++u) {
      int pc = g * 5 + u;
      bool on = pc < c;
      float4 ap4 = apv[u], he4 = hev[u];
      h0 = fmaf(on ? ap4.x : 1.f, h0, on ? he4.x : 0.f);
      h1 = fmaf(on ? ap4.y : 1.f, h1, on ? he4.y : 0.f);
      h2 = fmaf(on ? ap4.z : 1.f, h2, on ? he4.z : 0.f);
      h3 = fmaf(on ? ap4.w : 1.f, h3, on ? he4.w : 0.f);
    }
  }
  int t = b * SEQ + c * CHK;
  const float* dp = delta + (size_t)t * DI + d;
  const float* xp = xc + (size_t)t * DI + d;
  const float* bp = xdbl + (size_t)t * XD + DTR + ng * 4;
  const float* cp = xdbl + (size_t)t * XD + DTR + NST + ng * 4;
  const unsigned short* zp = xzb + (size_t)t * (2 * DI) + DI + d;
  unsigned short* yp = y + (size_t)t * DI + d;
  for (int lb = 0; lb < CHK; lb += 8) {
    float dvv[8], xvv[8], zvv[8];
    float4 Bv[8], Cv[8];
#pragma unroll
    for (int u = 0; u < 8; ++u) {
      dvv[u] = dp[(size_t)u * DI];
      xvv[u] = xp[(size_t)u * DI];
      Bv[u] = *(const float4*)(bp + u * XD);
      Cv[u] = *(const float4*)(cp + u * XD);
      zvv[u] = b2f(zp[(size_t)u * 2 * DI]);  // broadcast within 4-lane group
    }
#pragma unroll
    for (int u = 0; u < 8; ++u) {
      float dv = dvv[u], xv = xvv[u];
      float4 B4 = Bv[u], C4 = Cv[u];
      float dx = dv * xv;
      float e0 = __expf(dv * a0), e1 = __expf(dv * a1);
      float e2 = __expf(dv * a2), e3 = __expf(dv * a3);
      h0 = fmaf(e0, h0, dx * B4.x);
      h1 = fmaf(e1, h1, dx * B4.y);
      h2 = fmaf(e2, h2, dx * B4.z);
      h3 = fmaf(e3, h3, dx * B4.w);
      float contrib = h0 * C4.x + h1 * C4.y + h2 * C4.z + h3 * C4.w;
      contrib += __shfl_xor(contrib, 1);
      contrib += __shfl_xor(contrib, 2);
      if (ng == 0) {
        float zv = zvv[u];
        float sig = zv / (1.f + __expf(-zv));
        yp[(size_t)u * DI] = f2b((contrib + xv * dskip) * sig);
      }
    }
    dp += 8 * DI; xp += 8 * DI; bp += 8 * XD; cp += 8 * XD;
    zp += 8 * 2 * DI; yp += 8 * DI;
  }
}

// ---------------------------------------------------------------------------
extern "C" void kernel_launch(void* const* d_in, const int* in_sizes, int n_in,
                              void* d_out, int out_size, void* d_ws,
                              size_t ws_size, hipStream_t stream) {
  const float* x_in      = (const float*)d_in[0];
  const float* ln0_w     = (const float*)d_in[1];
  const float* ln0_b     = (const float*)d_in[2];
  const float* ln1_w     = (const float*)d_in[3];
  const float* ln1_b     = (const float*)d_in[4];
  const float* ln2_w     = (const float*)d_in[5];
  const float* ln2_b     = (const float*)d_in[6];
  const float* in_proj_w = (const float*)d_in[7];
  const float* conv_w    = (const float*)d_in[8];
  const float* conv_b    = (const float*)d_in[9];
  const float* x_proj_w  = (const float*)d_in[10];
  const float* dt_proj_w = (const float*)d_in[11];
  const float* dt_proj_b = (const float*)d_in[12];
  const float* A_log     = (const float*)d_in[13];
  const float* D_skip    = (const float*)d_in[14];
  const float* out_proj_w= (const float*)d_in[15];
  const float* ffn_w1    = (const float*)d_in[16];
  const float* ffn_b1    = (const float*)d_in[17];
  const float* ffn_w2    = (const float*)d_in[18];
  const float* ffn_b2    = (const float*)d_in[19];
  float* out = (float*)d_out;

  // Workspace layout (floats), liveness-aliased; total 20.12M floats = 80.5 MB
  float* ws    = (float*)d_ws;
  float* xws   = ws;                     // [T,DM] fp32 residual          2.097M
  float* big   = xws + 2097152;          // xzb bf16 [T,4096] / hbf bf16  4.194M
  float* r2    = big + 4194304;          // ybf bf16 [T,DI]               2.097M
  float* xcws  = r2 + 2097152;           // xc fp32 / bf16 split-K parts  4.194M
  float* xdbl  = xcws + 4194304;         // [T,96] fp32                   0.197M
  float* dws   = xdbl + 196608;          // xcb bf16 / delta fp32         4.194M
  float* ubf_f = dws + 4194304;          // [T,DM] bf16 LN out            1.049M
  float* wbf_f = ubf_f + 1048576;        // staging region                2.097M
  // aliases (timeline-checked):
  unsigned short* xzb  = (unsigned short*)big;   // in_proj out, dies after scan2
  unsigned short* hbf  = (unsigned short*)big;   // ffn1 -> ffn2 [T,FFN] bf16
  unsigned short* ybf  = (unsigned short*)r2;    // scan2 -> out_proj
  unsigned short* ubf  = (unsigned short*)ubf_f;
  unsigned short* xcb  = (unsigned short*)dws;   // conv bf16, dies before dt_proj
  unsigned short* pbf  = (unsigned short*)xcws;  // 4-layer bf16 partials [4][T,DM]
  unsigned short* wbf  = (unsigned short*)wbf_f;
  float* part  = wbf_f;                          // xproj partials [8][T,96] 1.573M
  unsigned short* wpb = (unsigned short*)(wbf_f + 1572864);  // x_proj_w bf16
  unsigned short* dtb = (unsigned short*)(wbf_f + 1671168);  // dt bf16 [T,64]
  unsigned short* dwb = (unsigned short*)(wbf_f + 1736704);  // dt_proj_w bf16
  // scan summaries overwrite the whole staging region after dt_proj:
  float* hend  = wbf_f;                  // [1048576] = B*NCHK*DI*NST
  float* aprod = wbf_f + 1048576;        // [1048576]

  // 1: convert in_proj_w -> bf16 (4096x1024)
  f2b_k<<<(4096 * 1024) / 1024, 256, 0, stream>>>(in_proj_w, wbf);
  // 2: fused LN0+LN1 -> xws fp32, ubf bf16
  ln01_k<<<T_TOK, 256, 0, stream>>>(x_in, ln0_w, ln0_b, ln1_w, ln1_b, xws, ubf);
  // 3: in_proj -> xzb bf16 (128x128 tiles, 512 blocks)
  {
    dim3 g((2 * DI) / 128, T_TOK / 128, 1);
    gemm_bf16<<<g, 256, 0, stream>>>(ubf, DM, wbf, DM, xzb, 2 * DI, DM, 1,
                                     nullptr, nullptr);
  }
  // 4: causal conv + silu (bf16 in) -> xc fp32 + xcb bf16
  conv_silu_k<<<(T_TOK * DI) / 256, 256, 0, stream>>>(xzb, conv_w, conv_b, xcws, xcb);
  // 5: x_proj + dt_proj weights -> bf16 (one dispatch)
  f2b2_k<<<(XD * DI + DI * DTR) / 1024, 256, 0, stream>>>(
      x_proj_w, wpb, (XD * DI) / 4, dt_proj_w, dwb);
  // 6: x_proj split-K MFMA + reduce -> xdbl fp32, dtb bf16
  {
    dim3 g(T_TOK / 64, SPLITK);
    xproj_k<<<g, 256, 0, stream>>>(xcb, wpb, part);
    xreduce_k<<<(T_TOK * XD) / 256, 256, 0, stream>>>(part, xdbl, dtb);
  }
  // 7: dt_proj + softplus -> delta fp32 (dedicated kernel, 512 blocks)
  {
    dim3 g(DI / 128, T_TOK / 64);
    dtproj_k<<<g, 256, 0, stream>>>(dtb, dwb, dws, dt_proj_b);
  }
  // 8-9: chunked scan, 4 states/thread (summaries alias dead staging region)
  {
    int nthreads = 2 * NCHK * DI * 4;  // 262144
    scan1_k<<<nthreads / 256, 256, 0, stream>>>(dws, xcws, xdbl, A_log,
                                                hend, aprod);
    scan2_k<<<nthreads / 256, 256, 0, stream>>>(dws, xcws, xdbl, xzb,
                                                A_log, D_skip, hend, aprod, ybf);
  }
  // 10: out_proj split-K x4 (bf16 partials in pbf) + fused reduce+res+LN2
  f2b_k<<<(DM * DI) / 1024, 256, 0, stream>>>(out_proj_w, wbf);
  {
    dim3 g(DM / 128, T_TOK / 128, 4);
    gemm_bf16<<<g, 256, 0, stream>>>(ybf, DI, wbf, DI, nullptr, DM, DI / 4, 8,
                                     nullptr, pbf);
    reduce4lnb_k<<<T_TOK, 256, 0, stream>>>(pbf, xws, ln2_w, ln2_b, ubf);
  }
  // 11: ffn1 + bias + gelu -> hbf bf16 (128x128 tiles, 512 blocks)
  f2b_k<<<(FFN * DM) / 1024, 256, 0, stream>>>(ffn_w1, wbf);
  {
    dim3 g(FFN / 128, T_TOK / 128, 1);
    gemm_bf16<<<g, 256, 0, stream>>>(ubf, DM, wbf, DM, hbf, FFN, DM, 2, ffn_b1,
                                     nullptr);
  }
  // 12: ffn2 split-K x4 (bf16 partials in pbf) + reduce(+bias+res) -> d_out
  f2b_k<<<(DM * FFN) / 1024, 256, 0, stream>>>(ffn_w2, wbf);
  {
    dim3 g(DM / 128, T_TOK / 128, 4);
    gemm_bf16<<<g, 256, 0, stream>>>(hbf, FFN, wbf, FFN, nullptr, DM, FFN / 4, 8,
                                     nullptr, pbf);
    reduce4b_k<<<(T_TOK * DM) / 1024, 256, 0, stream>>>(pbf, out, ffn_b2, xws);
  }
}